// Round 7
// baseline (276.218 us; speedup 1.0000x reference)
//
#include <hip/hip_runtime.h>
#include <math.h>

#define N_NODES 100000
#define N_EDGES 1600000
#define C 64
#define ROWS 64      // bucket row stride (u32); slots 0..62 used, 63 pad (uint4 alignment)
#define CAPN 63
#define NSTRIPE 32   // striped BN accumulators to avoid same-address atomic pileup
#define BN_EPS 1e-5f

// ws layout:
//   Bmat    : N*C floats     (x @ W2)                25.6 MB
//   bucket  : N*64 u32       (63 src slots + pad)    25.6 MB
//   cnt     : N u32          (degree counters)        0.4 MB
//   stripes : NSTRIPE*128 floats (striped S/Q sums)  16 KB
//   finals  : 128 floats     (S[64] then Q[64])      512 B

__global__ __launch_bounds__(256) void k_init(unsigned* __restrict__ cnt,
                                              float* __restrict__ stripes) {
    int i = blockIdx.x * blockDim.x + threadIdx.x;
    int stride = gridDim.x * blockDim.x;
    for (int p = i; p < N_NODES; p += stride) cnt[p] = 0u;
    if (blockIdx.x == 0) {
        for (int p = threadIdx.x; p < NSTRIPE * 128; p += 256) stripes[p] = 0.f;
    }
}

// CSR-lite build: 1 edge per thread. Payload store issued as atomicExch:
// memory-side atomics write 16B granules (measured round 2: 16B/atomic) vs
// ~60B/line for a plain scattered 4B store (measured round 6: 96MB WRITE).
__global__ __launch_bounds__(256) void k_bucket(const int* __restrict__ ei,
                                                unsigned* __restrict__ cnt,
                                                unsigned* __restrict__ bucket) {
    int e = blockIdx.x * blockDim.x + threadIdx.x;
    if (e >= N_EDGES) return;
    int src = ei[e];
    int dst = ei[N_EDGES + e];
    if ((unsigned)src >= N_NODES || (unsigned)dst >= N_NODES) return;  // fault guard
    unsigned pos = atomicAdd(&cnt[dst], 1u);
    if (pos < CAPN) atomicExch(&bucket[(size_t)dst * ROWS + pos], (unsigned)src);
}

// A' = x @ (W1 - W2) + b  -> out (d_out as scratch; fully rewritten later)
// B  = x @ W2             -> Bmat
__global__ __launch_bounds__(256) void k_gemm(const float* __restrict__ x,
                                              const float* __restrict__ W,
                                              const float* __restrict__ b,
                                              float* __restrict__ Ap,
                                              float* __restrict__ Bmat) {
    __shared__ float Wa[64 * 64];
    __shared__ float Wb[64 * 64];
    __shared__ float xs[32 * 64];
    int t = threadIdx.x;
    int base = blockIdx.x * 32;  // 100000 % 32 == 0 (3125 blocks)

    for (int p = t; p < 64 * 64; p += 256) {
        float w1 = W[p];
        float w2 = W[64 * 64 + p];
        Wb[p] = w2;
        Wa[p] = w1 - w2;
    }
    for (int p = t; p < 32 * 64; p += 256) {
        xs[p] = x[(size_t)base * 64 + p];
    }
    __syncthreads();

    int c = t & 63;
    int r = t >> 6;  // 0..3
    float bc = b[c];
    float accA[8], accB[8];
#pragma unroll
    for (int q = 0; q < 8; ++q) { accA[q] = bc; accB[q] = 0.f; }
#pragma unroll 4
    for (int k = 0; k < 64; ++k) {
        float wa = Wa[k * 64 + c];
        float wb = Wb[k * 64 + c];
#pragma unroll
        for (int q = 0; q < 8; ++q) {
            float xv = xs[(r + 4 * q) * 64 + k];
            accA[q] = fmaf(xv, wa, accA[q]);
            accB[q] = fmaf(xv, wb, accB[q]);
        }
    }
#pragma unroll
    for (int q = 0; q < 8; ++q) {
        int node = base + r + 4 * q;
        size_t p = (size_t)node * 64 + c;
        Ap[p] = accA[q];
        Bmat[p] = accB[q];
    }
}

__device__ __forceinline__ void vmax(float4& a, const float4& b) {
    a.x = fmaxf(a.x, b.x); a.y = fmaxf(a.y, b.y);
    a.z = fmaxf(a.z, b.z); a.w = fmaxf(a.w, b.w);
}

// gather-max per node (16 lanes/node, float4 per lane, 8 outstanding loads)
// + ELU + BN partial sums (register-accumulated, one striped flush per block)
__global__ __launch_bounds__(256) void k_gather(const unsigned* __restrict__ cnt,
                                                const unsigned* __restrict__ bucket,
                                                const float4* __restrict__ B4,
                                                float4* __restrict__ out4,
                                                float* __restrict__ stripes) {
    int t = threadIdx.x;
    int lane4 = t & 15;
    int g = t >> 4;  // 16 node-groups per block
    float4 s = make_float4(0.f, 0.f, 0.f, 0.f);
    float4 sq = make_float4(0.f, 0.f, 0.f, 0.f);

    for (int n = blockIdx.x * 16 + g; n < N_NODES; n += gridDim.x * 16) {
        int d = min((int)cnt[n], CAPN);
        float4 h;
        if (d == 0) {
            h = make_float4(0.f, 0.f, 0.f, 0.f);
        } else {
            float4 a = out4[(size_t)n * 16 + lane4];  // Ap — issued early, used late
            const unsigned* row = bucket + (size_t)n * ROWS;
            float4 mx = make_float4(-INFINITY, -INFINITY, -INFINITY, -INFINITY);
            int j = 0;
            for (; j + 8 <= d; j += 8) {
                uint4 i0 = *reinterpret_cast<const uint4*>(row + j);
                uint4 i1 = *reinterpret_cast<const uint4*>(row + j + 4);
                float4 v0 = B4[(size_t)i0.x * 16 + lane4];
                float4 v1 = B4[(size_t)i0.y * 16 + lane4];
                float4 v2 = B4[(size_t)i0.z * 16 + lane4];
                float4 v3 = B4[(size_t)i0.w * 16 + lane4];
                float4 v4 = B4[(size_t)i1.x * 16 + lane4];
                float4 v5 = B4[(size_t)i1.y * 16 + lane4];
                float4 v6 = B4[(size_t)i1.z * 16 + lane4];
                float4 v7 = B4[(size_t)i1.w * 16 + lane4];
                vmax(v0, v1); vmax(v2, v3); vmax(v4, v5); vmax(v6, v7);
                vmax(v0, v2); vmax(v4, v6); vmax(v0, v4); vmax(mx, v0);
            }
            for (; j < d; ++j) {
                float4 v = B4[(size_t)row[j] * 16 + lane4];
                vmax(mx, v);
            }
            float ax = a.x + mx.x, ay = a.y + mx.y, az = a.z + mx.z, aw = a.w + mx.w;
            h.x = ax > 0.f ? ax : (expf(ax) - 1.f);
            h.y = ay > 0.f ? ay : (expf(ay) - 1.f);
            h.z = az > 0.f ? az : (expf(az) - 1.f);
            h.w = aw > 0.f ? aw : (expf(aw) - 1.f);
        }
        out4[(size_t)n * 16 + lane4] = h;
        s.x += h.x; s.y += h.y; s.z += h.z; s.w += h.w;
        sq.x += h.x * h.x; sq.y += h.y * h.y; sq.z += h.z * h.z; sq.w += h.w * h.w;
    }

    __shared__ float4 ls[256];
    __shared__ float4 lq[256];
    ls[t] = s;
    lq[t] = sq;
    __syncthreads();
#pragma unroll
    for (int off = 8; off >= 1; off >>= 1) {
        if (g < off) {
            int o = t + off * 16;
            ls[t].x += ls[o].x; ls[t].y += ls[o].y; ls[t].z += ls[o].z; ls[t].w += ls[o].w;
            lq[t].x += lq[o].x; lq[t].y += lq[o].y; lq[t].z += lq[o].z; lq[t].w += lq[o].w;
        }
        __syncthreads();
    }
    if (g == 0) {
        float* sb = stripes + (blockIdx.x & (NSTRIPE - 1)) * 128;
        int c4 = lane4 * 4;
        atomicAdd(&sb[c4 + 0], ls[t].x);
        atomicAdd(&sb[c4 + 1], ls[t].y);
        atomicAdd(&sb[c4 + 2], ls[t].z);
        atomicAdd(&sb[c4 + 3], ls[t].w);
        atomicAdd(&sb[64 + c4 + 0], lq[t].x);
        atomicAdd(&sb[64 + c4 + 1], lq[t].y);
        atomicAdd(&sb[64 + c4 + 2], lq[t].z);
        atomicAdd(&sb[64 + c4 + 3], lq[t].w);
    }
}

// fold 32 stripes -> 128 finals
__global__ __launch_bounds__(128) void k_reduce(const float* __restrict__ stripes,
                                                float* __restrict__ finals) {
    int t = threadIdx.x;  // 0..127
    float acc = 0.f;
#pragma unroll
    for (int s = 0; s < NSTRIPE; ++s) acc += stripes[s * 128 + t];
    finals[t] = acc;
}

// out = gamma*(h-mean)*rsqrt(var+eps)+beta, in place, float4
__global__ __launch_bounds__(256) void k_bn(float4* __restrict__ out4,
                                            const float* __restrict__ finals,
                                            const float* __restrict__ gamma,
                                            const float* __restrict__ beta) {
    size_t i = (size_t)blockIdx.x * blockDim.x + threadIdx.x;
    size_t stride = (size_t)gridDim.x * blockDim.x;
    const float invN = 1.f / (float)N_NODES;
    size_t total4 = (size_t)N_NODES * C / 4;
    for (size_t p = i; p < total4; p += stride) {
        int c4 = (int)(p & 15) * 4;
        float4 h = out4[p];
        float4 o;
        float m, v, inv;
        m = finals[c4 + 0] * invN; v = finals[64 + c4 + 0] * invN - m * m; inv = rsqrtf(v + BN_EPS);
        o.x = gamma[c4 + 0] * (h.x - m) * inv + beta[c4 + 0];
        m = finals[c4 + 1] * invN; v = finals[64 + c4 + 1] * invN - m * m; inv = rsqrtf(v + BN_EPS);
        o.y = gamma[c4 + 1] * (h.y - m) * inv + beta[c4 + 1];
        m = finals[c4 + 2] * invN; v = finals[64 + c4 + 2] * invN - m * m; inv = rsqrtf(v + BN_EPS);
        o.z = gamma[c4 + 2] * (h.z - m) * inv + beta[c4 + 2];
        m = finals[c4 + 3] * invN; v = finals[64 + c4 + 3] * invN - m * m; inv = rsqrtf(v + BN_EPS);
        o.w = gamma[c4 + 3] * (h.w - m) * inv + beta[c4 + 3];
        out4[p] = o;
    }
}

extern "C" void kernel_launch(void* const* d_in, const int* in_sizes, int n_in,
                              void* d_out, int out_size, void* d_ws, size_t ws_size,
                              hipStream_t stream) {
    const float* x = (const float*)d_in[0];
    const int* ei = (const int*)d_in[1];  // int32 per harness contract
    const float* W = (const float*)d_in[2];
    const float* b = (const float*)d_in[3];
    const float* gamma = (const float*)d_in[4];
    const float* beta = (const float*)d_in[5];
    float* out = (float*)d_out;

    char* ws = (char*)d_ws;
    float* Bmat = (float*)ws;
    unsigned* bucket = (unsigned*)(ws + (size_t)N_NODES * C * 4);
    unsigned* cnt = (unsigned*)(ws + 2 * (size_t)N_NODES * C * 4);
    float* stripes = (float*)(ws + 2 * (size_t)N_NODES * C * 4 + (size_t)N_NODES * 4);
    float* finals = stripes + NSTRIPE * 128;

    k_init<<<512, 256, 0, stream>>>(cnt, stripes);
    k_bucket<<<(N_EDGES + 255) / 256, 256, 0, stream>>>(ei, cnt, bucket);
    k_gemm<<<N_NODES / 32, 256, 0, stream>>>(x, W, b, out, Bmat);
    k_gather<<<2048, 256, 0, stream>>>(cnt, bucket, (const float4*)Bmat, (float4*)out, stripes);
    k_reduce<<<1, 128, 0, stream>>>(stripes, finals);
    k_bn<<<2048, 256, 0, stream>>>((float4*)out, finals, gamma, beta);
}

// Round 8
// 172.317 us; speedup vs baseline: 1.6030x; 1.6030x over previous
//
#include <hip/hip_runtime.h>
#include <math.h>

#define N_NODES 100000
#define N_EDGES 1600000
#define C 64
#define NBKT 391        // buckets of 256 consecutive dst nodes (391*256 >= 100000)
#define BKT_CAP 8192    // per-bucket edge capacity (avg 4096, Poisson tail ~ +64 sigma)
#define TILE 8192       // edges per k_bin block-tile
#define MAXW 65         // LDS row stride (64 + 1 pad -> bank spread)
#define NSTRIPE 32
#define BN_EPS 1e-5f

// ws layout:
//   Bmat   : N*C floats                25.6 MB
//   binned : NBKT*BKT_CAP u32          12.8 MB   packed (dl<<17)|src
//   bcnt   : NBKT u32
//   stripes: NSTRIPE*128 floats
//   finals : 128 floats

__device__ __forceinline__ unsigned f2key(float x) {
    unsigned u = __float_as_uint(x);
    return (u & 0x80000000u) ? ~u : (u | 0x80000000u);
}
__device__ __forceinline__ float key2f(unsigned k) {
    unsigned u = (k & 0x80000000u) ? (k & 0x7fffffffu) : ~k;
    return __uint_as_float(u);
}
__device__ __forceinline__ float eluf(float x) {
    return x > 0.f ? x : (expf(x) - 1.f);
}

__global__ __launch_bounds__(256) void k_init(unsigned* __restrict__ bcnt,
                                              float* __restrict__ stripes) {
    int t = blockIdx.x * blockDim.x + threadIdx.x;
    if (t < NBKT) bcnt[t] = 0u;
    if (t < NSTRIPE * 128) stripes[t] = 0.f;
}

// Bin edges by dst>>8 into per-bucket contiguous runs.
// LDS histogram per tile -> one global region-claim atomic per (bucket,tile)
// -> placements are adjacent in address AND time => ~1x write amplification.
__global__ __launch_bounds__(256) void k_bin(const int* __restrict__ ei,
                                             unsigned* __restrict__ bcnt,
                                             unsigned* __restrict__ binned) {
    __shared__ unsigned hcnt[NBKT];
    __shared__ unsigned hbase[NBKT];
    int e0 = blockIdx.x * TILE;
    int ecount = min(TILE, N_EDGES - e0);
    if (ecount <= 0) return;

    for (int i = threadIdx.x; i < NBKT; i += 256) hcnt[i] = 0u;
    __syncthreads();
    // pass 1: histogram dst buckets
    for (int i = threadIdx.x; i < ecount; i += 256) {
        int dst = ei[N_EDGES + e0 + i];
        if ((unsigned)dst < N_NODES) atomicAdd(&hcnt[dst >> 8], 1u);
    }
    __syncthreads();
    // claim contiguous regions; reset cursors
    for (int i = threadIdx.x; i < NBKT; i += 256) {
        unsigned c = hcnt[i];
        hbase[i] = c ? atomicAdd(&bcnt[i], c) : 0u;
        hcnt[i] = 0u;
    }
    __syncthreads();
    // pass 2: place packed edges
    for (int i = threadIdx.x; i < ecount; i += 256) {
        int src = ei[e0 + i];
        int dst = ei[N_EDGES + e0 + i];
        if ((unsigned)src >= N_NODES || (unsigned)dst >= N_NODES) continue;
        int bk = dst >> 8;
        unsigned pos = hbase[bk] + atomicAdd(&hcnt[bk], 1u);
        if (pos < BKT_CAP)
            binned[(size_t)bk * BKT_CAP + pos] =
                ((unsigned)(dst & 255) << 17) | (unsigned)src;
    }
}

// A' = x @ (W1 - W2) + b  -> out (d_out as scratch; rewritten later)
// B  = x @ W2             -> Bmat
__global__ __launch_bounds__(256) void k_gemm(const float* __restrict__ x,
                                              const float* __restrict__ W,
                                              const float* __restrict__ b,
                                              float* __restrict__ Ap,
                                              float* __restrict__ Bmat) {
    __shared__ float Wa[64 * 64];
    __shared__ float Wb[64 * 64];
    __shared__ float xs[32 * 64];
    int t = threadIdx.x;
    int base = blockIdx.x * 32;

    for (int p = t; p < 64 * 64; p += 256) {
        float w1 = W[p];
        float w2 = W[64 * 64 + p];
        Wb[p] = w2;
        Wa[p] = w1 - w2;
    }
    for (int p = t; p < 32 * 64; p += 256) {
        xs[p] = x[(size_t)base * 64 + p];
    }
    __syncthreads();

    int c = t & 63;
    int r = t >> 6;
    float bc = b[c];
    float accA[8], accB[8];
#pragma unroll
    for (int q = 0; q < 8; ++q) { accA[q] = bc; accB[q] = 0.f; }
#pragma unroll 4
    for (int k = 0; k < 64; ++k) {
        float wa = Wa[k * 64 + c];
        float wb = Wb[k * 64 + c];
#pragma unroll
        for (int q = 0; q < 8; ++q) {
            float xv = xs[(r + 4 * q) * 64 + k];
            accA[q] = fmaf(xv, wa, accA[q]);
            accB[q] = fmaf(xv, wb, accB[q]);
        }
    }
#pragma unroll
    for (int q = 0; q < 8; ++q) {
        int node = base + r + 4 * q;
        size_t p = (size_t)node * 64 + c;
        Ap[p] = accA[q];
        Bmat[p] = accB[q];
    }
}

// One bucket (256 nodes) per block. LDS monotonic-u32 max accumulators
// (stride 65 -> conflict-free random-row atomics). Then ELU + BN partials.
__global__ __launch_bounds__(256) void k_fused(const unsigned* __restrict__ bcnt,
                                               const unsigned* __restrict__ binned,
                                               const float4* __restrict__ B4,
                                               float4* __restrict__ out4,
                                               float* __restrict__ stripes) {
    extern __shared__ unsigned mx[];  // 256*65 u32 = 66560 B
    int q = blockIdx.x;
    int t = threadIdx.x;
    int n0 = q * 256;
    int nspan = min(256, N_NODES - n0);

    for (int i = t; i < 256 * MAXW; i += 256) mx[i] = 0u;
    __syncthreads();

    unsigned cnt = min(bcnt[q], (unsigned)BKT_CAP);
    const unsigned* lst = binned + (size_t)q * BKT_CAP;
    for (unsigned i = t; i < cnt; i += 256) {
        unsigned p = lst[i];
        unsigned src = p & 0x1FFFFu;
        unsigned dl = p >> 17;
        const float4* brow = B4 + (size_t)src * 16;
        unsigned* row = mx + dl * MAXW;
#pragma unroll
        for (int k = 0; k < 16; ++k) {
            float4 v = brow[k];
            atomicMax(&row[4 * k + 0], f2key(v.x));
            atomicMax(&row[4 * k + 1], f2key(v.y));
            atomicMax(&row[4 * k + 2], f2key(v.z));
            atomicMax(&row[4 * k + 3], f2key(v.w));
        }
    }
    __syncthreads();

    // finish: 16 groups of 16 lanes; each group one node per iteration
    int lane4 = t & 15;
    int g = t >> 4;
    float4 s = make_float4(0.f, 0.f, 0.f, 0.f);
    float4 sq = make_float4(0.f, 0.f, 0.f, 0.f);
    for (int nl = g; nl < nspan; nl += 16) {
        int n = n0 + nl;
        const unsigned* row = mx + nl * MAXW + lane4 * 4;
        unsigned k0 = row[0], k1 = row[1], k2 = row[2], k3 = row[3];
        float4 a = out4[(size_t)n * 16 + lane4];  // Ap
        float4 h;
        h.x = (k0 == 0u) ? 0.f : eluf(a.x + key2f(k0));
        h.y = (k1 == 0u) ? 0.f : eluf(a.y + key2f(k1));
        h.z = (k2 == 0u) ? 0.f : eluf(a.z + key2f(k2));
        h.w = (k3 == 0u) ? 0.f : eluf(a.w + key2f(k3));
        out4[(size_t)n * 16 + lane4] = h;
        s.x += h.x; s.y += h.y; s.z += h.z; s.w += h.w;
        sq.x += h.x * h.x; sq.y += h.y * h.y; sq.z += h.z * h.z; sq.w += h.w * h.w;
    }
    __syncthreads();

    // block reduce (overlay onto mx) -> striped atomics
    float4* ls = (float4*)mx;        // 256 float4 = 4 KB
    float4* lq = ls + 256;           // 256 float4 = 4 KB (within 66.5 KB)
    ls[t] = s;
    lq[t] = sq;
    __syncthreads();
#pragma unroll
    for (int off = 8; off >= 1; off >>= 1) {
        if (g < off) {
            int o = t + off * 16;
            ls[t].x += ls[o].x; ls[t].y += ls[o].y; ls[t].z += ls[o].z; ls[t].w += ls[o].w;
            lq[t].x += lq[o].x; lq[t].y += lq[o].y; lq[t].z += lq[o].z; lq[t].w += lq[o].w;
        }
        __syncthreads();
    }
    if (g == 0) {
        float* sb = stripes + (q & (NSTRIPE - 1)) * 128;
        int c4 = lane4 * 4;
        atomicAdd(&sb[c4 + 0], ls[t].x);
        atomicAdd(&sb[c4 + 1], ls[t].y);
        atomicAdd(&sb[c4 + 2], ls[t].z);
        atomicAdd(&sb[c4 + 3], ls[t].w);
        atomicAdd(&sb[64 + c4 + 0], lq[t].x);
        atomicAdd(&sb[64 + c4 + 1], lq[t].y);
        atomicAdd(&sb[64 + c4 + 2], lq[t].z);
        atomicAdd(&sb[64 + c4 + 3], lq[t].w);
    }
}

// fold 32 stripes -> 128 finals
__global__ __launch_bounds__(128) void k_reduce(const float* __restrict__ stripes,
                                                float* __restrict__ finals) {
    int t = threadIdx.x;
    float acc = 0.f;
#pragma unroll
    for (int s = 0; s < NSTRIPE; ++s) acc += stripes[s * 128 + t];
    finals[t] = acc;
}

// out = gamma*(h-mean)*rsqrt(var+eps)+beta, in place
__global__ __launch_bounds__(256) void k_bn(float4* __restrict__ out4,
                                            const float* __restrict__ finals,
                                            const float* __restrict__ gamma,
                                            const float* __restrict__ beta) {
    size_t i = (size_t)blockIdx.x * blockDim.x + threadIdx.x;
    size_t stride = (size_t)gridDim.x * blockDim.x;
    const float invN = 1.f / (float)N_NODES;
    size_t total4 = (size_t)N_NODES * C / 4;
    for (size_t p = i; p < total4; p += stride) {
        int c4 = (int)(p & 15) * 4;
        float4 h = out4[p];
        float4 o;
        float m, v, inv;
        m = finals[c4 + 0] * invN; v = finals[64 + c4 + 0] * invN - m * m; inv = rsqrtf(v + BN_EPS);
        o.x = gamma[c4 + 0] * (h.x - m) * inv + beta[c4 + 0];
        m = finals[c4 + 1] * invN; v = finals[64 + c4 + 1] * invN - m * m; inv = rsqrtf(v + BN_EPS);
        o.y = gamma[c4 + 1] * (h.y - m) * inv + beta[c4 + 1];
        m = finals[c4 + 2] * invN; v = finals[64 + c4 + 2] * invN - m * m; inv = rsqrtf(v + BN_EPS);
        o.z = gamma[c4 + 2] * (h.z - m) * inv + beta[c4 + 2];
        m = finals[c4 + 3] * invN; v = finals[64 + c4 + 3] * invN - m * m; inv = rsqrtf(v + BN_EPS);
        o.w = gamma[c4 + 3] * (h.w - m) * inv + beta[c4 + 3];
        out4[p] = o;
    }
}

extern "C" void kernel_launch(void* const* d_in, const int* in_sizes, int n_in,
                              void* d_out, int out_size, void* d_ws, size_t ws_size,
                              hipStream_t stream) {
    const float* x = (const float*)d_in[0];
    const int* ei = (const int*)d_in[1];  // int32 per harness contract
    const float* W = (const float*)d_in[2];
    const float* b = (const float*)d_in[3];
    const float* gamma = (const float*)d_in[4];
    const float* beta = (const float*)d_in[5];
    float* out = (float*)d_out;

    char* ws = (char*)d_ws;
    float* Bmat = (float*)ws;
    unsigned* binned = (unsigned*)(ws + (size_t)N_NODES * C * 4);
    unsigned* bcnt = (unsigned*)(ws + (size_t)N_NODES * C * 4 + (size_t)NBKT * BKT_CAP * 4);
    float* stripes = (float*)((char*)bcnt + ((NBKT * 4 + 255) & ~255));
    float* finals = stripes + NSTRIPE * 128;

    k_init<<<(NSTRIPE * 128 + 255) / 256, 256, 0, stream>>>(bcnt, stripes);
    k_bin<<<(N_EDGES + TILE - 1) / TILE, 256, 0, stream>>>(ei, bcnt, binned);
    k_gemm<<<N_NODES / 32, 256, 0, stream>>>(x, W, b, out, Bmat);
    k_fused<<<NBKT, 256, 256 * MAXW * 4, stream>>>(bcnt, binned, (const float4*)Bmat,
                                                   (float4*)out, stripes);
    k_reduce<<<1, 128, 0, stream>>>(stripes, finals);
    k_bn<<<2048, 256, 0, stream>>>((float4*)out, finals, gamma, beta);
}

// Round 9
// 168.306 us; speedup vs baseline: 1.6412x; 1.0238x over previous
//
#include <hip/hip_runtime.h>
#include <math.h>

#define N_NODES 100000
#define N_EDGES 1600000
#define C 64
#define BKT_SHIFT 6
#define BKT_NODES 64          // nodes per bucket
#define NBKT 1563             // ceil(100000/64)
#define BKT_CAP 2048          // per-bucket edge capacity (avg 1024, +32 sigma)
#define TILE 8192             // edges per k_bin block-tile
#define MAXW 65               // LDS row stride (64 + 1 pad)
#define NSTRIPE 32
#define BN_EPS 1e-5f

// ws layout:
//   Bmat   : N*C floats                25.6 MB
//   binned : NBKT*BKT_CAP u32          12.8 MB   packed (dl<<17)|src
//   bcnt   : NBKT u32
//   stripes: NSTRIPE*128 floats
//   finals : 128 floats

__device__ __forceinline__ unsigned f2key(float x) {
    unsigned u = __float_as_uint(x);
    return (u & 0x80000000u) ? ~u : (u | 0x80000000u);
}
__device__ __forceinline__ float key2f(unsigned k) {
    unsigned u = (k & 0x80000000u) ? (k & 0x7fffffffu) : ~k;
    return __uint_as_float(u);
}
__device__ __forceinline__ float eluf(float x) {
    return x > 0.f ? x : (expf(x) - 1.f);
}

__global__ __launch_bounds__(256) void k_init(unsigned* __restrict__ bcnt,
                                              float* __restrict__ stripes) {
    int t = blockIdx.x * blockDim.x + threadIdx.x;
    if (t < NBKT) bcnt[t] = 0u;
    if (t < NSTRIPE * 128) stripes[t] = 0.f;
}

// Bin edges by dst>>6 into per-bucket contiguous runs.
// LDS histogram per tile -> one global region-claim atomic per (bucket,tile)
// -> placements adjacent in address AND time => ~1x write amplification.
__global__ __launch_bounds__(256) void k_bin(const int* __restrict__ ei,
                                             unsigned* __restrict__ bcnt,
                                             unsigned* __restrict__ binned) {
    __shared__ unsigned hcnt[NBKT];
    __shared__ unsigned hbase[NBKT];
    int e0 = blockIdx.x * TILE;
    int ecount = min(TILE, N_EDGES - e0);
    if (ecount <= 0) return;

    for (int i = threadIdx.x; i < NBKT; i += 256) hcnt[i] = 0u;
    __syncthreads();
    for (int i = threadIdx.x; i < ecount; i += 256) {
        int dst = ei[N_EDGES + e0 + i];
        if ((unsigned)dst < N_NODES) atomicAdd(&hcnt[dst >> BKT_SHIFT], 1u);
    }
    __syncthreads();
    for (int i = threadIdx.x; i < NBKT; i += 256) {
        unsigned c = hcnt[i];
        hbase[i] = c ? atomicAdd(&bcnt[i], c) : 0u;
        hcnt[i] = 0u;
    }
    __syncthreads();
    for (int i = threadIdx.x; i < ecount; i += 256) {
        int src = ei[e0 + i];
        int dst = ei[N_EDGES + e0 + i];
        if ((unsigned)src >= N_NODES || (unsigned)dst >= N_NODES) continue;
        int bk = dst >> BKT_SHIFT;
        unsigned pos = hbase[bk] + atomicAdd(&hcnt[bk], 1u);
        if (pos < BKT_CAP)
            binned[(size_t)bk * BKT_CAP + pos] =
                ((unsigned)(dst & (BKT_NODES - 1)) << 17) | (unsigned)src;
    }
}

// A' = x @ (W1 - W2) + b  -> out (d_out as scratch; rewritten later)
// B  = x @ W2             -> Bmat
__global__ __launch_bounds__(256) void k_gemm(const float* __restrict__ x,
                                              const float* __restrict__ W,
                                              const float* __restrict__ b,
                                              float* __restrict__ Ap,
                                              float* __restrict__ Bmat) {
    __shared__ float Wa[64 * 64];
    __shared__ float Wb[64 * 64];
    __shared__ float xs[32 * 64];
    int t = threadIdx.x;
    int base = blockIdx.x * 32;

    for (int p = t; p < 64 * 64; p += 256) {
        float w1 = W[p];
        float w2 = W[64 * 64 + p];
        Wb[p] = w2;
        Wa[p] = w1 - w2;
    }
    for (int p = t; p < 32 * 64; p += 256) {
        xs[p] = x[(size_t)base * 64 + p];
    }
    __syncthreads();

    int c = t & 63;
    int r = t >> 6;
    float bc = b[c];
    float accA[8], accB[8];
#pragma unroll
    for (int q = 0; q < 8; ++q) { accA[q] = bc; accB[q] = 0.f; }
#pragma unroll 4
    for (int k = 0; k < 64; ++k) {
        float wa = Wa[k * 64 + c];
        float wb = Wb[k * 64 + c];
#pragma unroll
        for (int q = 0; q < 8; ++q) {
            float xv = xs[(r + 4 * q) * 64 + k];
            accA[q] = fmaf(xv, wa, accA[q]);
            accB[q] = fmaf(xv, wb, accB[q]);
        }
    }
#pragma unroll
    for (int q = 0; q < 8; ++q) {
        int node = base + r + 4 * q;
        size_t p = (size_t)node * 64 + c;
        Ap[p] = accA[q];
        Bmat[p] = accB[q];
    }
}

// One bucket (64 nodes) per block, 16.6 KB LDS -> ~6 blocks/CU resident.
// LDS monotonic-u32 max accumulators, then ELU + BN partials.
__global__ __launch_bounds__(256) void k_fused(const unsigned* __restrict__ bcnt,
                                               const unsigned* __restrict__ binned,
                                               const float4* __restrict__ B4,
                                               float4* __restrict__ out4,
                                               float* __restrict__ stripes) {
    extern __shared__ unsigned mx[];  // BKT_NODES*MAXW u32 = 16640 B
    int q = blockIdx.x;
    int t = threadIdx.x;
    int n0 = q * BKT_NODES;
    int nspan = min(BKT_NODES, N_NODES - n0);

    for (int i = t; i < BKT_NODES * MAXW; i += 256) mx[i] = 0u;
    __syncthreads();

    unsigned cnt = min(bcnt[q], (unsigned)BKT_CAP);
    const unsigned* lst = binned + (size_t)q * BKT_CAP;
    for (unsigned i = t; i < cnt; i += 256) {
        unsigned p = lst[i];
        unsigned src = p & 0x1FFFFu;
        unsigned dl = p >> 17;
        const float4* brow = B4 + (size_t)src * 16;
        unsigned* row = mx + dl * MAXW;
#pragma unroll
        for (int k = 0; k < 16; ++k) {
            float4 v = brow[k];
            atomicMax(&row[4 * k + 0], f2key(v.x));
            atomicMax(&row[4 * k + 1], f2key(v.y));
            atomicMax(&row[4 * k + 2], f2key(v.z));
            atomicMax(&row[4 * k + 3], f2key(v.w));
        }
    }
    __syncthreads();

    // finish: 16 groups of 16 lanes; each group one node per iteration
    int lane4 = t & 15;
    int g = t >> 4;
    float4 s = make_float4(0.f, 0.f, 0.f, 0.f);
    float4 sq = make_float4(0.f, 0.f, 0.f, 0.f);
    for (int nl = g; nl < nspan; nl += 16) {
        int n = n0 + nl;
        const unsigned* row = mx + nl * MAXW + lane4 * 4;
        unsigned k0 = row[0], k1 = row[1], k2 = row[2], k3 = row[3];
        float4 a = out4[(size_t)n * 16 + lane4];  // Ap
        float4 h;
        h.x = (k0 == 0u) ? 0.f : eluf(a.x + key2f(k0));
        h.y = (k1 == 0u) ? 0.f : eluf(a.y + key2f(k1));
        h.z = (k2 == 0u) ? 0.f : eluf(a.z + key2f(k2));
        h.w = (k3 == 0u) ? 0.f : eluf(a.w + key2f(k3));
        out4[(size_t)n * 16 + lane4] = h;
        s.x += h.x; s.y += h.y; s.z += h.z; s.w += h.w;
        sq.x += h.x * h.x; sq.y += h.y * h.y; sq.z += h.z * h.z; sq.w += h.w * h.w;
    }
    __syncthreads();

    // block reduce (overlay onto mx) -> striped atomics
    float4* ls = (float4*)mx;        // 256 float4 = 4 KB
    float4* lq = ls + 256;           // 4 KB (within 16.6 KB)
    ls[t] = s;
    lq[t] = sq;
    __syncthreads();
#pragma unroll
    for (int off = 8; off >= 1; off >>= 1) {
        if (g < off) {
            int o = t + off * 16;
            ls[t].x += ls[o].x; ls[t].y += ls[o].y; ls[t].z += ls[o].z; ls[t].w += ls[o].w;
            lq[t].x += lq[o].x; lq[t].y += lq[o].y; lq[t].z += lq[o].z; lq[t].w += lq[o].w;
        }
        __syncthreads();
    }
    if (g == 0) {
        float* sb = stripes + (q & (NSTRIPE - 1)) * 128;
        int c4 = lane4 * 4;
        atomicAdd(&sb[c4 + 0], ls[t].x);
        atomicAdd(&sb[c4 + 1], ls[t].y);
        atomicAdd(&sb[c4 + 2], ls[t].z);
        atomicAdd(&sb[c4 + 3], ls[t].w);
        atomicAdd(&sb[64 + c4 + 0], lq[t].x);
        atomicAdd(&sb[64 + c4 + 1], lq[t].y);
        atomicAdd(&sb[64 + c4 + 2], lq[t].z);
        atomicAdd(&sb[64 + c4 + 3], lq[t].w);
    }
}

// fold 32 stripes -> 128 finals
__global__ __launch_bounds__(128) void k_reduce(const float* __restrict__ stripes,
                                                float* __restrict__ finals) {
    int t = threadIdx.x;
    float acc = 0.f;
#pragma unroll
    for (int s = 0; s < NSTRIPE; ++s) acc += stripes[s * 128 + t];
    finals[t] = acc;
}

// out = gamma*(h-mean)*rsqrt(var+eps)+beta, in place
__global__ __launch_bounds__(256) void k_bn(float4* __restrict__ out4,
                                            const float* __restrict__ finals,
                                            const float* __restrict__ gamma,
                                            const float* __restrict__ beta) {
    size_t i = (size_t)blockIdx.x * blockDim.x + threadIdx.x;
    size_t stride = (size_t)gridDim.x * blockDim.x;
    const float invN = 1.f / (float)N_NODES;
    size_t total4 = (size_t)N_NODES * C / 4;
    for (size_t p = i; p < total4; p += stride) {
        int c4 = (int)(p & 15) * 4;
        float4 h = out4[p];
        float4 o;
        float m, v, inv;
        m = finals[c4 + 0] * invN; v = finals[64 + c4 + 0] * invN - m * m; inv = rsqrtf(v + BN_EPS);
        o.x = gamma[c4 + 0] * (h.x - m) * inv + beta[c4 + 0];
        m = finals[c4 + 1] * invN; v = finals[64 + c4 + 1] * invN - m * m; inv = rsqrtf(v + BN_EPS);
        o.y = gamma[c4 + 1] * (h.y - m) * inv + beta[c4 + 1];
        m = finals[c4 + 2] * invN; v = finals[64 + c4 + 2] * invN - m * m; inv = rsqrtf(v + BN_EPS);
        o.z = gamma[c4 + 2] * (h.z - m) * inv + beta[c4 + 2];
        m = finals[c4 + 3] * invN; v = finals[64 + c4 + 3] * invN - m * m; inv = rsqrtf(v + BN_EPS);
        o.w = gamma[c4 + 3] * (h.w - m) * inv + beta[c4 + 3];
        out4[p] = o;
    }
}

extern "C" void kernel_launch(void* const* d_in, const int* in_sizes, int n_in,
                              void* d_out, int out_size, void* d_ws, size_t ws_size,
                              hipStream_t stream) {
    const float* x = (const float*)d_in[0];
    const int* ei = (const int*)d_in[1];  // int32 per harness contract
    const float* W = (const float*)d_in[2];
    const float* b = (const float*)d_in[3];
    const float* gamma = (const float*)d_in[4];
    const float* beta = (const float*)d_in[5];
    float* out = (float*)d_out;

    char* ws = (char*)d_ws;
    float* Bmat = (float*)ws;
    unsigned* binned = (unsigned*)(ws + (size_t)N_NODES * C * 4);
    unsigned* bcnt = (unsigned*)(ws + (size_t)N_NODES * C * 4 + (size_t)NBKT * BKT_CAP * 4);
    float* stripes = (float*)((char*)bcnt + ((NBKT * 4 + 255) & ~255));
    float* finals = stripes + NSTRIPE * 128;

    k_init<<<(NSTRIPE * 128 + NBKT + 255) / 256, 256, 0, stream>>>(bcnt, stripes);
    k_bin<<<(N_EDGES + TILE - 1) / TILE, 256, 0, stream>>>(ei, bcnt, binned);
    k_gemm<<<N_NODES / 32, 256, 0, stream>>>(x, W, b, out, Bmat);
    k_fused<<<NBKT, 256, BKT_NODES * MAXW * 4, stream>>>(bcnt, binned, (const float4*)Bmat,
                                                         (float4*)out, stripes);
    k_reduce<<<1, 128, 0, stream>>>(stripes, finals);
    k_bn<<<2048, 256, 0, stream>>>((float4*)out, finals, gamma, beta);
}

// Round 10
// 136.840 us; speedup vs baseline: 2.0185x; 1.2299x over previous
//
#include <hip/hip_runtime.h>
#include <math.h>

#define N_NODES 100000
#define N_EDGES 1600000
#define C 64
#define BKT_SHIFT 6
#define BKT_NODES 64          // nodes per bucket
#define NBKT 1563             // ceil(100000/64)
#define BKT_CAP 2048          // per-bucket edge capacity (avg 1024, +32 sigma)
#define TILE 8192             // edges per k_bin block-tile
#define MAXW 65               // LDS row stride (64 + 1 pad)
#define NSTRIPE 32
#define BN_EPS 1e-5f

// ws layout:
//   Bkey   : N*32 u32 (bf16 key-packed x@W2, 2 ch/u32)   12.8 MB
//   binned : NBKT*BKT_CAP u32  packed (dl<<17)|src        12.8 MB
//   bcnt   : NBKT u32
//   stripes: NSTRIPE*128 floats
//   finals : 128 floats

__device__ __forceinline__ float eluf(float x) {
    return x > 0.f ? x : (expf(x) - 1.f);
}

// key16 (monotonic bf16) -> f32 value
__device__ __forceinline__ float key32_to_f(unsigned k32) {
    unsigned k16 = k32 >> 16;
    unsigned u16 = (k16 & 0x8000u) ? (k16 & 0x7FFFu) : (~k16 & 0xFFFFu);
    return __uint_as_float(u16 << 16);
}

__global__ __launch_bounds__(256) void k_init(unsigned* __restrict__ bcnt,
                                              float* __restrict__ stripes) {
    int t = blockIdx.x * blockDim.x + threadIdx.x;
    if (t < NBKT) bcnt[t] = 0u;
    if (t < NSTRIPE * 128) stripes[t] = 0.f;
}

// Bin edges by dst>>6 into per-bucket contiguous runs (round-8 scheme).
__global__ __launch_bounds__(256) void k_bin(const int* __restrict__ ei,
                                             unsigned* __restrict__ bcnt,
                                             unsigned* __restrict__ binned) {
    __shared__ unsigned hcnt[NBKT];
    __shared__ unsigned hbase[NBKT];
    int e0 = blockIdx.x * TILE;
    int ecount = min(TILE, N_EDGES - e0);
    if (ecount <= 0) return;

    for (int i = threadIdx.x; i < NBKT; i += 256) hcnt[i] = 0u;
    __syncthreads();
    for (int i = threadIdx.x; i < ecount; i += 256) {
        int dst = ei[N_EDGES + e0 + i];
        if ((unsigned)dst < N_NODES) atomicAdd(&hcnt[dst >> BKT_SHIFT], 1u);
    }
    __syncthreads();
    for (int i = threadIdx.x; i < NBKT; i += 256) {
        unsigned c = hcnt[i];
        hbase[i] = c ? atomicAdd(&bcnt[i], c) : 0u;
        hcnt[i] = 0u;
    }
    __syncthreads();
    for (int i = threadIdx.x; i < ecount; i += 256) {
        int src = ei[e0 + i];
        int dst = ei[N_EDGES + e0 + i];
        if ((unsigned)src >= N_NODES || (unsigned)dst >= N_NODES) continue;
        int bk = dst >> BKT_SHIFT;
        unsigned pos = hbase[bk] + atomicAdd(&hcnt[bk], 1u);
        if (pos < BKT_CAP)
            binned[(size_t)bk * BKT_CAP + pos] =
                ((unsigned)(dst & (BKT_NODES - 1)) << 17) | (unsigned)src;
    }
}

// A' = x @ (W1 - W2) + b  -> out (d_out as scratch; rewritten later)
// B  = x @ W2 -> bf16 RNE -> monotonic key16, packed 2 channels per u32.
__global__ __launch_bounds__(256) void k_gemm(const float* __restrict__ x,
                                              const float* __restrict__ W,
                                              const float* __restrict__ b,
                                              float* __restrict__ Ap,
                                              unsigned* __restrict__ Bkey) {
    __shared__ float Wa[64 * 64];
    __shared__ float Wb[64 * 64];
    __shared__ float xs[32 * 64];
    int t = threadIdx.x;
    int base = blockIdx.x * 32;

    for (int p = t; p < 64 * 64; p += 256) {
        float w1 = W[p];
        float w2 = W[64 * 64 + p];
        Wb[p] = w2;
        Wa[p] = w1 - w2;
    }
    for (int p = t; p < 32 * 64; p += 256) {
        xs[p] = x[(size_t)base * 64 + p];
    }
    __syncthreads();

    int c = t & 63;
    int r = t >> 6;
    float bc = b[c];
    float accA[8], accB[8];
#pragma unroll
    for (int q = 0; q < 8; ++q) { accA[q] = bc; accB[q] = 0.f; }
#pragma unroll 4
    for (int k = 0; k < 64; ++k) {
        float wa = Wa[k * 64 + c];
        float wb = Wb[k * 64 + c];
#pragma unroll
        for (int q = 0; q < 8; ++q) {
            float xv = xs[(r + 4 * q) * 64 + k];
            accA[q] = fmaf(xv, wa, accA[q]);
            accB[q] = fmaf(xv, wb, accB[q]);
        }
    }
#pragma unroll
    for (int q = 0; q < 8; ++q) {
        int node = base + r + 4 * q;
        Ap[(size_t)node * 64 + c] = accA[q];
        // bf16 RNE + monotonic key transform
        unsigned full = __float_as_uint(accB[q]);
        unsigned r16 = (full + 0x7FFFu + ((full >> 16) & 1u)) >> 16;
        unsigned key16 = (r16 & 0x8000u) ? (~r16 & 0xFFFFu) : (r16 | 0x8000u);
        unsigned other = (unsigned)__shfl_xor((int)key16, 1, 64);
        if ((c & 1) == 0)
            Bkey[(size_t)node * 32 + (c >> 1)] = key16 | (other << 16);
    }
}

// One bucket (64 nodes) per block, 16.6 KB LDS. Gather 128 B/edge (bf16 keys),
// LDS atomicMax in key space (pre-keyed: unpack = shift/and only).
__global__ __launch_bounds__(256) void k_fused(const unsigned* __restrict__ bcnt,
                                               const unsigned* __restrict__ binned,
                                               const unsigned* __restrict__ Bkey,
                                               float4* __restrict__ out4,
                                               float* __restrict__ stripes) {
    extern __shared__ unsigned mx[];  // BKT_NODES*MAXW u32 = 16640 B
    int q = blockIdx.x;
    int t = threadIdx.x;
    int n0 = q * BKT_NODES;
    int nspan = min(BKT_NODES, N_NODES - n0);

    for (int i = t; i < BKT_NODES * MAXW; i += 256) mx[i] = 0u;
    __syncthreads();

    unsigned cnt = min(bcnt[q], (unsigned)BKT_CAP);
    const unsigned* lst = binned + (size_t)q * BKT_CAP;
    for (unsigned i = t; i < cnt; i += 256) {
        unsigned p = lst[i];
        unsigned src = p & 0x1FFFFu;
        unsigned dl = p >> 17;
        const uint4* brow = (const uint4*)(Bkey + (size_t)src * 32);
        unsigned* row = mx + dl * MAXW;
#pragma unroll
        for (int k = 0; k < 8; ++k) {
            uint4 w = brow[k];
            atomicMax(&row[8 * k + 0], w.x << 16);
            atomicMax(&row[8 * k + 1], w.x & 0xFFFF0000u);
            atomicMax(&row[8 * k + 2], w.y << 16);
            atomicMax(&row[8 * k + 3], w.y & 0xFFFF0000u);
            atomicMax(&row[8 * k + 4], w.z << 16);
            atomicMax(&row[8 * k + 5], w.z & 0xFFFF0000u);
            atomicMax(&row[8 * k + 6], w.w << 16);
            atomicMax(&row[8 * k + 7], w.w & 0xFFFF0000u);
        }
    }
    __syncthreads();

    // finish: 16 groups of 16 lanes; each group one node per iteration
    int lane4 = t & 15;
    int g = t >> 4;
    float4 s = make_float4(0.f, 0.f, 0.f, 0.f);
    float4 sq = make_float4(0.f, 0.f, 0.f, 0.f);
    for (int nl = g; nl < nspan; nl += 16) {
        int n = n0 + nl;
        const unsigned* row = mx + nl * MAXW + lane4 * 4;
        unsigned k0 = row[0], k1 = row[1], k2 = row[2], k3 = row[3];
        float4 a = out4[(size_t)n * 16 + lane4];  // Ap
        float4 h;
        h.x = (k0 == 0u) ? 0.f : eluf(a.x + key32_to_f(k0));
        h.y = (k1 == 0u) ? 0.f : eluf(a.y + key32_to_f(k1));
        h.z = (k2 == 0u) ? 0.f : eluf(a.z + key32_to_f(k2));
        h.w = (k3 == 0u) ? 0.f : eluf(a.w + key32_to_f(k3));
        out4[(size_t)n * 16 + lane4] = h;
        s.x += h.x; s.y += h.y; s.z += h.z; s.w += h.w;
        sq.x += h.x * h.x; sq.y += h.y * h.y; sq.z += h.z * h.z; sq.w += h.w * h.w;
    }
    __syncthreads();

    // block reduce (overlay onto mx) -> striped atomics
    float4* ls = (float4*)mx;        // 4 KB
    float4* lq = ls + 256;           // 4 KB (within 16.6 KB)
    ls[t] = s;
    lq[t] = sq;
    __syncthreads();
#pragma unroll
    for (int off = 8; off >= 1; off >>= 1) {
        if (g < off) {
            int o = t + off * 16;
            ls[t].x += ls[o].x; ls[t].y += ls[o].y; ls[t].z += ls[o].z; ls[t].w += ls[o].w;
            lq[t].x += lq[o].x; lq[t].y += lq[o].y; lq[t].z += lq[o].z; lq[t].w += lq[o].w;
        }
        __syncthreads();
    }
    if (g == 0) {
        float* sb = stripes + (q & (NSTRIPE - 1)) * 128;
        int c4 = lane4 * 4;
        atomicAdd(&sb[c4 + 0], ls[t].x);
        atomicAdd(&sb[c4 + 1], ls[t].y);
        atomicAdd(&sb[c4 + 2], ls[t].z);
        atomicAdd(&sb[c4 + 3], ls[t].w);
        atomicAdd(&sb[64 + c4 + 0], lq[t].x);
        atomicAdd(&sb[64 + c4 + 1], lq[t].y);
        atomicAdd(&sb[64 + c4 + 2], lq[t].z);
        atomicAdd(&sb[64 + c4 + 3], lq[t].w);
    }
}

// fold 32 stripes -> 128 finals
__global__ __launch_bounds__(128) void k_reduce(const float* __restrict__ stripes,
                                                float* __restrict__ finals) {
    int t = threadIdx.x;
    float acc = 0.f;
#pragma unroll
    for (int s = 0; s < NSTRIPE; ++s) acc += stripes[s * 128 + t];
    finals[t] = acc;
}

// out = gamma*(h-mean)*rsqrt(var+eps)+beta, in place
__global__ __launch_bounds__(256) void k_bn(float4* __restrict__ out4,
                                            const float* __restrict__ finals,
                                            const float* __restrict__ gamma,
                                            const float* __restrict__ beta) {
    size_t i = (size_t)blockIdx.x * blockDim.x + threadIdx.x;
    size_t stride = (size_t)gridDim.x * blockDim.x;
    const float invN = 1.f / (float)N_NODES;
    size_t total4 = (size_t)N_NODES * C / 4;
    for (size_t p = i; p < total4; p += stride) {
        int c4 = (int)(p & 15) * 4;
        float4 h = out4[p];
        float4 o;
        float m, v, inv;
        m = finals[c4 + 0] * invN; v = finals[64 + c4 + 0] * invN - m * m; inv = rsqrtf(v + BN_EPS);
        o.x = gamma[c4 + 0] * (h.x - m) * inv + beta[c4 + 0];
        m = finals[c4 + 1] * invN; v = finals[64 + c4 + 1] * invN - m * m; inv = rsqrtf(v + BN_EPS);
        o.y = gamma[c4 + 1] * (h.y - m) * inv + beta[c4 + 1];
        m = finals[c4 + 2] * invN; v = finals[64 + c4 + 2] * invN - m * m; inv = rsqrtf(v + BN_EPS);
        o.z = gamma[c4 + 2] * (h.z - m) * inv + beta[c4 + 2];
        m = finals[c4 + 3] * invN; v = finals[64 + c4 + 3] * invN - m * m; inv = rsqrtf(v + BN_EPS);
        o.w = gamma[c4 + 3] * (h.w - m) * inv + beta[c4 + 3];
        out4[p] = o;
    }
}

extern "C" void kernel_launch(void* const* d_in, const int* in_sizes, int n_in,
                              void* d_out, int out_size, void* d_ws, size_t ws_size,
                              hipStream_t stream) {
    const float* x = (const float*)d_in[0];
    const int* ei = (const int*)d_in[1];  // int32 per harness contract
    const float* W = (const float*)d_in[2];
    const float* b = (const float*)d_in[3];
    const float* gamma = (const float*)d_in[4];
    const float* beta = (const float*)d_in[5];
    float* out = (float*)d_out;

    char* ws = (char*)d_ws;
    unsigned* Bkey = (unsigned*)ws;                                   // 12.8 MB
    unsigned* binned = (unsigned*)(ws + (size_t)N_NODES * 32 * 4);    // 12.8 MB
    unsigned* bcnt = (unsigned*)((char*)binned + (size_t)NBKT * BKT_CAP * 4);
    float* stripes = (float*)((char*)bcnt + ((NBKT * 4 + 255) & ~255));
    float* finals = stripes + NSTRIPE * 128;

    k_init<<<(NSTRIPE * 128 + NBKT + 255) / 256, 256, 0, stream>>>(bcnt, stripes);
    k_bin<<<(N_EDGES + TILE - 1) / TILE, 256, 0, stream>>>(ei, bcnt, binned);
    k_gemm<<<N_NODES / 32, 256, 0, stream>>>(x, W, b, out, Bkey);
    k_fused<<<NBKT, 256, BKT_NODES * MAXW * 4, stream>>>(bcnt, binned, Bkey,
                                                         (float4*)out, stripes);
    k_reduce<<<1, 128, 0, stream>>>(stripes, finals);
    k_bn<<<2048, 256, 0, stream>>>((float4*)out, finals, gamma, beta);
}

// Round 11
// 123.328 us; speedup vs baseline: 2.2397x; 1.1096x over previous
//
#include <hip/hip_runtime.h>
#include <math.h>

#define N_NODES 100000
#define N_EDGES 1600000
#define C 64
#define BKT_SHIFT 6
#define BKT_NODES 64          // nodes per bucket
#define NBKT 1563             // ceil(100000/64)
#define BKT_CAP 2048          // per-bucket edge capacity (avg 1024, +32 sigma)
#define TILE 8192             // edges per k_bin block-tile
#define BIN_THREADS 1024      // 16 waves/block: hide LDS-atomic + scatter latency
#define MAXW 65               // LDS row stride (64 + 1 pad)
#define NSTRIPE 32
#define BN_EPS 1e-5f

// ws layout:
//   Bkey   : N*32 u32 (bf16 key-packed x@W2, 2 ch/u32)   12.8 MB
//   binned : NBKT*BKT_CAP u32  packed (dl<<17)|src        12.8 MB
//   bcnt   : NBKT u32
//   stripes: NSTRIPE*128 floats
//   finals : 128 floats

__device__ __forceinline__ float eluf(float x) {
    return x > 0.f ? x : (expf(x) - 1.f);
}

// key16 (monotonic bf16) -> f32 value
__device__ __forceinline__ float key32_to_f(unsigned k32) {
    unsigned k16 = k32 >> 16;
    unsigned u16 = (k16 & 0x8000u) ? (k16 & 0x7FFFu) : (~k16 & 0xFFFFu);
    return __uint_as_float(u16 << 16);
}

__global__ __launch_bounds__(256) void k_init(unsigned* __restrict__ bcnt,
                                              float* __restrict__ stripes) {
    int t = blockIdx.x * blockDim.x + threadIdx.x;
    if (t < NBKT) bcnt[t] = 0u;
    if (t < NSTRIPE * 128) stripes[t] = 0.f;
}

// Bin edges by dst>>6 into per-bucket contiguous runs.
// 1024 threads/block: same TILE (clustering preserved), 4x the waves in
// flight to hide LDS-atomic chains and scattered-store latency.
__global__ __launch_bounds__(BIN_THREADS) void k_bin(const int* __restrict__ ei,
                                                     unsigned* __restrict__ bcnt,
                                                     unsigned* __restrict__ binned) {
    __shared__ unsigned hcnt[NBKT];
    __shared__ unsigned hbase[NBKT];
    int e0 = blockIdx.x * TILE;
    int ecount = min(TILE, N_EDGES - e0);
    if (ecount <= 0) return;

    for (int i = threadIdx.x; i < NBKT; i += BIN_THREADS) hcnt[i] = 0u;
    __syncthreads();
    for (int i = threadIdx.x; i < ecount; i += BIN_THREADS) {
        int dst = ei[N_EDGES + e0 + i];
        if ((unsigned)dst < N_NODES) atomicAdd(&hcnt[dst >> BKT_SHIFT], 1u);
    }
    __syncthreads();
    for (int i = threadIdx.x; i < NBKT; i += BIN_THREADS) {
        unsigned c = hcnt[i];
        hbase[i] = c ? atomicAdd(&bcnt[i], c) : 0u;
        hcnt[i] = 0u;
    }
    __syncthreads();
    for (int i = threadIdx.x; i < ecount; i += BIN_THREADS) {
        int src = ei[e0 + i];
        int dst = ei[N_EDGES + e0 + i];
        if ((unsigned)src >= N_NODES || (unsigned)dst >= N_NODES) continue;
        int bk = dst >> BKT_SHIFT;
        unsigned pos = hbase[bk] + atomicAdd(&hcnt[bk], 1u);
        if (pos < BKT_CAP)
            binned[(size_t)bk * BKT_CAP + pos] =
                ((unsigned)(dst & (BKT_NODES - 1)) << 17) | (unsigned)src;
    }
}

// A' = x @ (W1 - W2) + b  -> out (d_out as scratch; rewritten later)
// B  = x @ W2 -> bf16 RNE -> monotonic key16, packed 2 channels per u32.
__global__ __launch_bounds__(256) void k_gemm(const float* __restrict__ x,
                                              const float* __restrict__ W,
                                              const float* __restrict__ b,
                                              float* __restrict__ Ap,
                                              unsigned* __restrict__ Bkey) {
    __shared__ float Wa[64 * 64];
    __shared__ float Wb[64 * 64];
    __shared__ float xs[32 * 64];
    int t = threadIdx.x;
    int base = blockIdx.x * 32;

    for (int p = t; p < 64 * 64; p += 256) {
        float w1 = W[p];
        float w2 = W[64 * 64 + p];
        Wb[p] = w2;
        Wa[p] = w1 - w2;
    }
    for (int p = t; p < 32 * 64; p += 256) {
        xs[p] = x[(size_t)base * 64 + p];
    }
    __syncthreads();

    int c = t & 63;
    int r = t >> 6;
    float bc = b[c];
    float accA[8], accB[8];
#pragma unroll
    for (int q = 0; q < 8; ++q) { accA[q] = bc; accB[q] = 0.f; }
#pragma unroll 4
    for (int k = 0; k < 64; ++k) {
        float wa = Wa[k * 64 + c];
        float wb = Wb[k * 64 + c];
#pragma unroll
        for (int q = 0; q < 8; ++q) {
            float xv = xs[(r + 4 * q) * 64 + k];
            accA[q] = fmaf(xv, wa, accA[q]);
            accB[q] = fmaf(xv, wb, accB[q]);
        }
    }
#pragma unroll
    for (int q = 0; q < 8; ++q) {
        int node = base + r + 4 * q;
        Ap[(size_t)node * 64 + c] = accA[q];
        // bf16 RNE + monotonic key transform
        unsigned full = __float_as_uint(accB[q]);
        unsigned r16 = (full + 0x7FFFu + ((full >> 16) & 1u)) >> 16;
        unsigned key16 = (r16 & 0x8000u) ? (~r16 & 0xFFFFu) : (r16 | 0x8000u);
        unsigned other = (unsigned)__shfl_xor((int)key16, 1, 64);
        if ((c & 1) == 0)
            Bkey[(size_t)node * 32 + (c >> 1)] = key16 | (other << 16);
    }
}

// One bucket (64 nodes) per block, 16.6 KB LDS. Gather 128 B/edge (bf16 keys),
// LDS atomicMax in key space (pre-keyed: unpack = shift/and only).
__global__ __launch_bounds__(256) void k_fused(const unsigned* __restrict__ bcnt,
                                               const unsigned* __restrict__ binned,
                                               const unsigned* __restrict__ Bkey,
                                               float4* __restrict__ out4,
                                               float* __restrict__ stripes) {
    extern __shared__ unsigned mx[];  // BKT_NODES*MAXW u32 = 16640 B
    int q = blockIdx.x;
    int t = threadIdx.x;
    int n0 = q * BKT_NODES;
    int nspan = min(BKT_NODES, N_NODES - n0);

    for (int i = t; i < BKT_NODES * MAXW; i += 256) mx[i] = 0u;
    __syncthreads();

    unsigned cnt = min(bcnt[q], (unsigned)BKT_CAP);
    const unsigned* lst = binned + (size_t)q * BKT_CAP;
    for (unsigned i = t; i < cnt; i += 256) {
        unsigned p = lst[i];
        unsigned src = p & 0x1FFFFu;
        unsigned dl = p >> 17;
        const uint4* brow = (const uint4*)(Bkey + (size_t)src * 32);
        unsigned* row = mx + dl * MAXW;
#pragma unroll
        for (int k = 0; k < 8; ++k) {
            uint4 w = brow[k];
            atomicMax(&row[8 * k + 0], w.x << 16);
            atomicMax(&row[8 * k + 1], w.x & 0xFFFF0000u);
            atomicMax(&row[8 * k + 2], w.y << 16);
            atomicMax(&row[8 * k + 3], w.y & 0xFFFF0000u);
            atomicMax(&row[8 * k + 4], w.z << 16);
            atomicMax(&row[8 * k + 5], w.z & 0xFFFF0000u);
            atomicMax(&row[8 * k + 6], w.w << 16);
            atomicMax(&row[8 * k + 7], w.w & 0xFFFF0000u);
        }
    }
    __syncthreads();

    // finish: 16 groups of 16 lanes; each group one node per iteration
    int lane4 = t & 15;
    int g = t >> 4;
    float4 s = make_float4(0.f, 0.f, 0.f, 0.f);
    float4 sq = make_float4(0.f, 0.f, 0.f, 0.f);
    for (int nl = g; nl < nspan; nl += 16) {
        int n = n0 + nl;
        const unsigned* row = mx + nl * MAXW + lane4 * 4;
        unsigned k0 = row[0], k1 = row[1], k2 = row[2], k3 = row[3];
        float4 a = out4[(size_t)n * 16 + lane4];  // Ap
        float4 h;
        h.x = (k0 == 0u) ? 0.f : eluf(a.x + key32_to_f(k0));
        h.y = (k1 == 0u) ? 0.f : eluf(a.y + key32_to_f(k1));
        h.z = (k2 == 0u) ? 0.f : eluf(a.z + key32_to_f(k2));
        h.w = (k3 == 0u) ? 0.f : eluf(a.w + key32_to_f(k3));
        out4[(size_t)n * 16 + lane4] = h;
        s.x += h.x; s.y += h.y; s.z += h.z; s.w += h.w;
        sq.x += h.x * h.x; sq.y += h.y * h.y; sq.z += h.z * h.z; sq.w += h.w * h.w;
    }
    __syncthreads();

    // block reduce (overlay onto mx) -> striped atomics
    float4* ls = (float4*)mx;        // 4 KB
    float4* lq = ls + 256;           // 4 KB (within 16.6 KB)
    ls[t] = s;
    lq[t] = sq;
    __syncthreads();
#pragma unroll
    for (int off = 8; off >= 1; off >>= 1) {
        if (g < off) {
            int o = t + off * 16;
            ls[t].x += ls[o].x; ls[t].y += ls[o].y; ls[t].z += ls[o].z; ls[t].w += ls[o].w;
            lq[t].x += lq[o].x; lq[t].y += lq[o].y; lq[t].z += lq[o].z; lq[t].w += lq[o].w;
        }
        __syncthreads();
    }
    if (g == 0) {
        float* sb = stripes + (q & (NSTRIPE - 1)) * 128;
        int c4 = lane4 * 4;
        atomicAdd(&sb[c4 + 0], ls[t].x);
        atomicAdd(&sb[c4 + 1], ls[t].y);
        atomicAdd(&sb[c4 + 2], ls[t].z);
        atomicAdd(&sb[c4 + 3], ls[t].w);
        atomicAdd(&sb[64 + c4 + 0], lq[t].x);
        atomicAdd(&sb[64 + c4 + 1], lq[t].y);
        atomicAdd(&sb[64 + c4 + 2], lq[t].z);
        atomicAdd(&sb[64 + c4 + 3], lq[t].w);
    }
}

// fold 32 stripes -> 128 finals
__global__ __launch_bounds__(128) void k_reduce(const float* __restrict__ stripes,
                                                float* __restrict__ finals) {
    int t = threadIdx.x;
    float acc = 0.f;
#pragma unroll
    for (int s = 0; s < NSTRIPE; ++s) acc += stripes[s * 128 + t];
    finals[t] = acc;
}

// out = gamma*(h-mean)*rsqrt(var+eps)+beta, in place
__global__ __launch_bounds__(256) void k_bn(float4* __restrict__ out4,
                                            const float* __restrict__ finals,
                                            const float* __restrict__ gamma,
                                            const float* __restrict__ beta) {
    size_t i = (size_t)blockIdx.x * blockDim.x + threadIdx.x;
    size_t stride = (size_t)gridDim.x * blockDim.x;
    const float invN = 1.f / (float)N_NODES;
    size_t total4 = (size_t)N_NODES * C / 4;
    for (size_t p = i; p < total4; p += stride) {
        int c4 = (int)(p & 15) * 4;
        float4 h = out4[p];
        float4 o;
        float m, v, inv;
        m = finals[c4 + 0] * invN; v = finals[64 + c4 + 0] * invN - m * m; inv = rsqrtf(v + BN_EPS);
        o.x = gamma[c4 + 0] * (h.x - m) * inv + beta[c4 + 0];
        m = finals[c4 + 1] * invN; v = finals[64 + c4 + 1] * invN - m * m; inv = rsqrtf(v + BN_EPS);
        o.y = gamma[c4 + 1] * (h.y - m) * inv + beta[c4 + 1];
        m = finals[c4 + 2] * invN; v = finals[64 + c4 + 2] * invN - m * m; inv = rsqrtf(v + BN_EPS);
        o.z = gamma[c4 + 2] * (h.z - m) * inv + beta[c4 + 2];
        m = finals[c4 + 3] * invN; v = finals[64 + c4 + 3] * invN - m * m; inv = rsqrtf(v + BN_EPS);
        o.w = gamma[c4 + 3] * (h.w - m) * inv + beta[c4 + 3];
        out4[p] = o;
    }
}

extern "C" void kernel_launch(void* const* d_in, const int* in_sizes, int n_in,
                              void* d_out, int out_size, void* d_ws, size_t ws_size,
                              hipStream_t stream) {
    const float* x = (const float*)d_in[0];
    const int* ei = (const int*)d_in[1];  // int32 per harness contract
    const float* W = (const float*)d_in[2];
    const float* b = (const float*)d_in[3];
    const float* gamma = (const float*)d_in[4];
    const float* beta = (const float*)d_in[5];
    float* out = (float*)d_out;

    char* ws = (char*)d_ws;
    unsigned* Bkey = (unsigned*)ws;                                   // 12.8 MB
    unsigned* binned = (unsigned*)(ws + (size_t)N_NODES * 32 * 4);    // 12.8 MB
    unsigned* bcnt = (unsigned*)((char*)binned + (size_t)NBKT * BKT_CAP * 4);
    float* stripes = (float*)((char*)bcnt + ((NBKT * 4 + 255) & ~255));
    float* finals = stripes + NSTRIPE * 128;

    k_init<<<(NSTRIPE * 128 + NBKT + 255) / 256, 256, 0, stream>>>(bcnt, stripes);
    k_bin<<<(N_EDGES + TILE - 1) / TILE, BIN_THREADS, 0, stream>>>(ei, bcnt, binned);
    k_gemm<<<N_NODES / 32, 256, 0, stream>>>(x, W, b, out, Bkey);
    k_fused<<<NBKT, 256, BKT_NODES * MAXW * 4, stream>>>(bcnt, binned, Bkey,
                                                         (float4*)out, stripes);
    k_reduce<<<1, 128, 0, stream>>>(stripes, finals);
    k_bn<<<2048, 256, 0, stream>>>((float4*)out, finals, gamma, beta);
}

// Round 12
// 109.570 us; speedup vs baseline: 2.5209x; 1.1256x over previous
//
#include <hip/hip_runtime.h>
#include <math.h>

#define N_NODES 100000
#define N_EDGES 1600000
#define C 64
#define BKT_SHIFT 6
#define BKT_NODES 64          // nodes per bucket
#define NBKT 1563             // ceil(100000/64)
#define BKT_CAP 2048          // per-bucket edge capacity (avg 1024, +32 sigma)
#define TILE 8192             // edges per k_bin block-tile
#define BIN_THREADS 1024      // 16 waves/block
#define MAXW 65               // LDS row stride (64 + 1 pad; 65%32=1 -> 2-way = free)
#define NSTRIPE 32
#define BN_EPS 1e-5f

// ws layout:
//   Bkey   : N*32 u32 (bf16 key-packed x@W2, 2 ch/u32)   12.8 MB
//   binned : NBKT*BKT_CAP u32  packed (dl<<17)|src        12.8 MB
//   Apb    : N*32 u32 (bf16-packed A' = x@(W1-W2)+b)      12.8 MB
//   hpk    : N*32 u32 (bf16-packed h, pre-BN)             12.8 MB
//   bcnt   : NBKT u32
//   stripes: NSTRIPE*128 floats
//   finals : 128 floats

__device__ __forceinline__ float eluf(float x) {
    return x > 0.f ? x : (expf(x) - 1.f);
}

// key16 (monotonic bf16) in high half of u32 -> f32 value
__device__ __forceinline__ float key32_to_f(unsigned k32) {
    unsigned k16 = k32 >> 16;
    unsigned u16 = (k16 & 0x8000u) ? (k16 & 0x7FFFu) : (~k16 & 0xFFFFu);
    return __uint_as_float(u16 << 16);
}
// bf16 RNE round of f32, returns u16 pattern
__device__ __forceinline__ unsigned bf16rne(float f) {
    unsigned u = __float_as_uint(f);
    return (u + 0x7FFFu + ((u >> 16) & 1u)) >> 16;
}
__device__ __forceinline__ float bf16lo_f(unsigned w) { return __uint_as_float((w & 0xFFFFu) << 16); }
__device__ __forceinline__ float bf16hi_f(unsigned w) { return __uint_as_float(w & 0xFFFF0000u); }

__global__ __launch_bounds__(256) void k_init(unsigned* __restrict__ bcnt,
                                              float* __restrict__ stripes) {
    int t = blockIdx.x * blockDim.x + threadIdx.x;
    if (t < NBKT) bcnt[t] = 0u;
    if (t < NSTRIPE * 128) stripes[t] = 0.f;
}

// Bin edges by dst>>6 into per-bucket contiguous runs.
__global__ __launch_bounds__(BIN_THREADS) void k_bin(const int* __restrict__ ei,
                                                     unsigned* __restrict__ bcnt,
                                                     unsigned* __restrict__ binned) {
    __shared__ unsigned hcnt[NBKT];
    __shared__ unsigned hbase[NBKT];
    int e0 = blockIdx.x * TILE;
    int ecount = min(TILE, N_EDGES - e0);
    if (ecount <= 0) return;

    for (int i = threadIdx.x; i < NBKT; i += BIN_THREADS) hcnt[i] = 0u;
    __syncthreads();
    for (int i = threadIdx.x; i < ecount; i += BIN_THREADS) {
        int dst = ei[N_EDGES + e0 + i];
        if ((unsigned)dst < N_NODES) atomicAdd(&hcnt[dst >> BKT_SHIFT], 1u);
    }
    __syncthreads();
    for (int i = threadIdx.x; i < NBKT; i += BIN_THREADS) {
        unsigned c = hcnt[i];
        hbase[i] = c ? atomicAdd(&bcnt[i], c) : 0u;
        hcnt[i] = 0u;
    }
    __syncthreads();
    for (int i = threadIdx.x; i < ecount; i += BIN_THREADS) {
        int src = ei[e0 + i];
        int dst = ei[N_EDGES + e0 + i];
        if ((unsigned)src >= N_NODES || (unsigned)dst >= N_NODES) continue;
        int bk = dst >> BKT_SHIFT;
        unsigned pos = hbase[bk] + atomicAdd(&hcnt[bk], 1u);
        if (pos < BKT_CAP)
            binned[(size_t)bk * BKT_CAP + pos] =
                ((unsigned)(dst & (BKT_NODES - 1)) << 17) | (unsigned)src;
    }
}

// A' = x @ (W1 - W2) + b -> Apb (bf16 packed)
// B  = x @ W2 -> bf16 RNE -> monotonic key16, packed 2 ch per u32 -> Bkey
__global__ __launch_bounds__(256) void k_gemm(const float* __restrict__ x,
                                              const float* __restrict__ W,
                                              const float* __restrict__ b,
                                              unsigned* __restrict__ Apb,
                                              unsigned* __restrict__ Bkey) {
    __shared__ float Wa[64 * 64];
    __shared__ float Wb[64 * 64];
    __shared__ float xs[32 * 64];
    int t = threadIdx.x;
    int base = blockIdx.x * 32;

    for (int p = t; p < 64 * 64; p += 256) {
        float w1 = W[p];
        float w2 = W[64 * 64 + p];
        Wb[p] = w2;
        Wa[p] = w1 - w2;
    }
    for (int p = t; p < 32 * 64; p += 256) {
        xs[p] = x[(size_t)base * 64 + p];
    }
    __syncthreads();

    int c = t & 63;
    int r = t >> 6;
    float bc = b[c];
    float accA[8], accB[8];
#pragma unroll
    for (int q = 0; q < 8; ++q) { accA[q] = bc; accB[q] = 0.f; }
#pragma unroll 4
    for (int k = 0; k < 64; ++k) {
        float wa = Wa[k * 64 + c];
        float wb = Wb[k * 64 + c];
#pragma unroll
        for (int q = 0; q < 8; ++q) {
            float xv = xs[(r + 4 * q) * 64 + k];
            accA[q] = fmaf(xv, wa, accA[q]);
            accB[q] = fmaf(xv, wb, accB[q]);
        }
    }
#pragma unroll
    for (int q = 0; q < 8; ++q) {
        int node = base + r + 4 * q;
        // A' -> bf16 pack (2 ch / u32)
        unsigned a16 = bf16rne(accA[q]);
        unsigned aOther = (unsigned)__shfl_xor((int)a16, 1, 64);
        // B -> bf16 RNE + monotonic key transform, pack
        unsigned r16 = bf16rne(accB[q]);
        unsigned key16 = (r16 & 0x8000u) ? (~r16 & 0xFFFFu) : (r16 | 0x8000u);
        unsigned kOther = (unsigned)__shfl_xor((int)key16, 1, 64);
        if ((c & 1) == 0) {
            Apb[(size_t)node * 32 + (c >> 1)] = a16 | (aOther << 16);
            Bkey[(size_t)node * 32 + (c >> 1)] = key16 | (kOther << 16);
        }
    }
}

// One bucket (64 nodes) per block. Cooperative row gather: 4 lanes/edge,
// each lane 2 x uint4 -> exactly 2 coalesced 64B line requests per edge.
// LDS atomicMax in key space; finish = ELU + bf16 h + BN partials.
__global__ __launch_bounds__(256) void k_fused(const unsigned* __restrict__ bcnt,
                                               const unsigned* __restrict__ binned,
                                               const unsigned* __restrict__ Bkey,
                                               const unsigned* __restrict__ Apb,
                                               unsigned* __restrict__ hpk,
                                               float* __restrict__ stripes) {
    extern __shared__ unsigned mx[];  // BKT_NODES*MAXW u32 = 16640 B
    int q = blockIdx.x;
    int t = threadIdx.x;
    int n0 = q * BKT_NODES;
    int nspan = min(BKT_NODES, N_NODES - n0);

    for (int i = t; i < BKT_NODES * MAXW; i += 256) mx[i] = 0u;
    __syncthreads();

    unsigned cnt = min(bcnt[q], (unsigned)BKT_CAP);
    const unsigned* lst = binned + (size_t)q * BKT_CAP;
    int ls = t & 3;  // lane-sub within 4-lane edge group
    for (unsigned i = (unsigned)(t >> 2); i < cnt; i += 64) {
        unsigned p = lst[i];
        unsigned src = p & 0x1FFFFu;
        unsigned dl = p >> 17;
        const uint4* bk = (const uint4*)(Bkey + (size_t)src * 32);
        uint4 w0 = bk[ls];       // bytes ls*16   : line 0 of row (coalesced)
        uint4 w1 = bk[4 + ls];   // bytes 64+ls*16: line 1 of row (coalesced)
        unsigned* row = mx + dl * MAXW;
        int s0 = ls * 8;
        atomicMax(&row[s0 + 0], w0.x << 16);
        atomicMax(&row[s0 + 1], w0.x & 0xFFFF0000u);
        atomicMax(&row[s0 + 2], w0.y << 16);
        atomicMax(&row[s0 + 3], w0.y & 0xFFFF0000u);
        atomicMax(&row[s0 + 4], w0.z << 16);
        atomicMax(&row[s0 + 5], w0.z & 0xFFFF0000u);
        atomicMax(&row[s0 + 6], w0.w << 16);
        atomicMax(&row[s0 + 7], w0.w & 0xFFFF0000u);
        int s1 = 32 + ls * 8;
        atomicMax(&row[s1 + 0], w1.x << 16);
        atomicMax(&row[s1 + 1], w1.x & 0xFFFF0000u);
        atomicMax(&row[s1 + 2], w1.y << 16);
        atomicMax(&row[s1 + 3], w1.y & 0xFFFF0000u);
        atomicMax(&row[s1 + 4], w1.z << 16);
        atomicMax(&row[s1 + 5], w1.z & 0xFFFF0000u);
        atomicMax(&row[s1 + 6], w1.w << 16);
        atomicMax(&row[s1 + 7], w1.w & 0xFFFF0000u);
    }
    __syncthreads();

    // finish: 16 groups of 16 lanes; each group one node per iteration
    int lane4 = t & 15;
    int g = t >> 4;
    float4 s = make_float4(0.f, 0.f, 0.f, 0.f);
    float4 sq = make_float4(0.f, 0.f, 0.f, 0.f);
    for (int nl = g; nl < nspan; nl += 16) {
        int n = n0 + nl;
        const unsigned* row = mx + nl * MAXW + lane4 * 4;
        unsigned k0 = row[0], k1 = row[1], k2 = row[2], k3 = row[3];
        uint2 ap = *reinterpret_cast<const uint2*>(Apb + (size_t)n * 32 + lane4 * 2);
        float h0 = (k0 == 0u) ? 0.f : eluf(bf16lo_f(ap.x) + key32_to_f(k0));
        float h1 = (k1 == 0u) ? 0.f : eluf(bf16hi_f(ap.x) + key32_to_f(k1));
        float h2 = (k2 == 0u) ? 0.f : eluf(bf16lo_f(ap.y) + key32_to_f(k2));
        float h3 = (k3 == 0u) ? 0.f : eluf(bf16hi_f(ap.y) + key32_to_f(k3));
        // quantize h to bf16 (stored form); accumulate BN stats on stored values
        unsigned q0 = bf16rne(h0), q1 = bf16rne(h1), q2 = bf16rne(h2), q3 = bf16rne(h3);
        uint2 hp;
        hp.x = q0 | (q1 << 16);
        hp.y = q2 | (q3 << 16);
        *reinterpret_cast<uint2*>(hpk + (size_t)n * 32 + lane4 * 2) = hp;
        float f0 = __uint_as_float(q0 << 16), f1 = __uint_as_float(q1 << 16);
        float f2 = __uint_as_float(q2 << 16), f3 = __uint_as_float(q3 << 16);
        s.x += f0; s.y += f1; s.z += f2; s.w += f3;
        sq.x += f0 * f0; sq.y += f1 * f1; sq.z += f2 * f2; sq.w += f3 * f3;
    }
    __syncthreads();

    // block reduce (overlay onto mx) -> striped atomics
    float4* lsum = (float4*)mx;
    float4* lqum = lsum + 256;
    lsum[t] = s;
    lqum[t] = sq;
    __syncthreads();
#pragma unroll
    for (int off = 8; off >= 1; off >>= 1) {
        if (g < off) {
            int o = t + off * 16;
            lsum[t].x += lsum[o].x; lsum[t].y += lsum[o].y; lsum[t].z += lsum[o].z; lsum[t].w += lsum[o].w;
            lqum[t].x += lqum[o].x; lqum[t].y += lqum[o].y; lqum[t].z += lqum[o].z; lqum[t].w += lqum[o].w;
        }
        __syncthreads();
    }
    if (g == 0) {
        float* sb = stripes + (q & (NSTRIPE - 1)) * 128;
        int c4 = lane4 * 4;
        atomicAdd(&sb[c4 + 0], lsum[t].x);
        atomicAdd(&sb[c4 + 1], lsum[t].y);
        atomicAdd(&sb[c4 + 2], lsum[t].z);
        atomicAdd(&sb[c4 + 3], lsum[t].w);
        atomicAdd(&sb[64 + c4 + 0], lqum[t].x);
        atomicAdd(&sb[64 + c4 + 1], lqum[t].y);
        atomicAdd(&sb[64 + c4 + 2], lqum[t].z);
        atomicAdd(&sb[64 + c4 + 3], lqum[t].w);
    }
}

// fold 32 stripes -> 128 finals
__global__ __launch_bounds__(128) void k_reduce(const float* __restrict__ stripes,
                                                float* __restrict__ finals) {
    int t = threadIdx.x;
    float acc = 0.f;
#pragma unroll
    for (int s = 0; s < NSTRIPE; ++s) acc += stripes[s * 128 + t];
    finals[t] = acc;
}

// out = gamma*(h-mean)*rsqrt(var+eps)+beta; reads bf16-packed h, writes f32
__global__ __launch_bounds__(256) void k_bn(const uint2* __restrict__ hpk2,
                                            const float* __restrict__ finals,
                                            const float* __restrict__ gamma,
                                            const float* __restrict__ beta,
                                            float4* __restrict__ out4) {
    size_t i = (size_t)blockIdx.x * blockDim.x + threadIdx.x;
    size_t stride = (size_t)gridDim.x * blockDim.x;
    const float invN = 1.f / (float)N_NODES;
    size_t total4 = (size_t)N_NODES * C / 4;
    for (size_t p = i; p < total4; p += stride) {
        int c4 = (int)(p & 15) * 4;
        uint2 hp = hpk2[p];
        float hx = bf16lo_f(hp.x), hy = bf16hi_f(hp.x);
        float hz = bf16lo_f(hp.y), hw = bf16hi_f(hp.y);
        float4 o;
        float m, v, inv;
        m = finals[c4 + 0] * invN; v = finals[64 + c4 + 0] * invN - m * m; inv = rsqrtf(v + BN_EPS);
        o.x = gamma[c4 + 0] * (hx - m) * inv + beta[c4 + 0];
        m = finals[c4 + 1] * invN; v = finals[64 + c4 + 1] * invN - m * m; inv = rsqrtf(v + BN_EPS);
        o.y = gamma[c4 + 1] * (hy - m) * inv + beta[c4 + 1];
        m = finals[c4 + 2] * invN; v = finals[64 + c4 + 2] * invN - m * m; inv = rsqrtf(v + BN_EPS);
        o.z = gamma[c4 + 2] * (hz - m) * inv + beta[c4 + 2];
        m = finals[c4 + 3] * invN; v = finals[64 + c4 + 3] * invN - m * m; inv = rsqrtf(v + BN_EPS);
        o.w = gamma[c4 + 3] * (hw - m) * inv + beta[c4 + 3];
        out4[p] = o;
    }
}

extern "C" void kernel_launch(void* const* d_in, const int* in_sizes, int n_in,
                              void* d_out, int out_size, void* d_ws, size_t ws_size,
                              hipStream_t stream) {
    const float* x = (const float*)d_in[0];
    const int* ei = (const int*)d_in[1];  // int32 per harness contract
    const float* W = (const float*)d_in[2];
    const float* b = (const float*)d_in[3];
    const float* gamma = (const float*)d_in[4];
    const float* beta = (const float*)d_in[5];
    float* out = (float*)d_out;

    char* ws = (char*)d_ws;
    unsigned* Bkey = (unsigned*)ws;                                        // 12.8 MB
    unsigned* binned = (unsigned*)(ws + (size_t)N_NODES * 32 * 4);         // 12.8 MB
    unsigned* Apb = (unsigned*)((char*)binned + (size_t)NBKT * BKT_CAP * 4);   // 12.8 MB
    unsigned* hpk = Apb + (size_t)N_NODES * 32;                            // 12.8 MB
    unsigned* bcnt = hpk + (size_t)N_NODES * 32;
    float* stripes = (float*)((char*)bcnt + ((NBKT * 4 + 255) & ~255));
    float* finals = stripes + NSTRIPE * 128;

    k_init<<<(NSTRIPE * 128 + NBKT + 255) / 256, 256, 0, stream>>>(bcnt, stripes);
    k_bin<<<(N_EDGES + TILE - 1) / TILE, BIN_THREADS, 0, stream>>>(ei, bcnt, binned);
    k_gemm<<<N_NODES / 32, 256, 0, stream>>>(x, W, b, Apb, Bkey);
    k_fused<<<NBKT, 256, BKT_NODES * MAXW * 4, stream>>>(bcnt, binned, Bkey, Apb, hpk, stripes);
    k_reduce<<<1, 128, 0, stream>>>(stripes, finals);
    k_bn<<<2048, 256, 0, stream>>>((const uint2*)hpk, finals, gamma, beta, (float4*)out);
}

// Round 13
// 92.677 us; speedup vs baseline: 2.9804x; 1.1823x over previous
//
#include <hip/hip_runtime.h>
#include <math.h>

#define N_NODES 100000
#define N_EDGES 1600000
#define C 64
#define BKT_SHIFT 6
#define BKT_NODES 64          // nodes per bucket
#define NBKT 1563             // ceil(100000/64)
#define BKT_CAP 2048          // per-bucket edge capacity (avg 1024, +32 sigma)
#define TILE 8192             // edges per k_bin block-tile
#define BIN_THREADS 1024      // 16 waves/block
#define MAXW 65               // LDS row stride (64 + 1 pad; 2-way = free)
#define NSTRIPE 32
#define XSTR 72               // LDS ushort row stride: 144 B = 16B-aligned, +4 banks/row
#define BN_EPS 1e-5f

typedef __attribute__((ext_vector_type(8))) short short8;   // 8 bf16 = 4 VGPR (MFMA A/B frag)
typedef __attribute__((ext_vector_type(4))) float f32x4;    // MFMA C/D frag

// ws layout:
//   Bkey   : N*32 u32 (bf16 key-packed x@W2, 2 ch/u32)   12.8 MB
//   binned : NBKT*BKT_CAP u32  packed (dl<<17)|src        12.8 MB
//   Apb    : N*32 u32 (bf16-packed A' = x@(W1-W2)+b)      12.8 MB
//   hpk    : N*32 u32 (bf16-packed h, pre-BN)             12.8 MB
//   bcnt   : NBKT u32
//   stripes: NSTRIPE*128 floats
//   finals : 128 floats

__device__ __forceinline__ float eluf(float x) {
    return x > 0.f ? x : (expf(x) - 1.f);
}

// key16 (monotonic bf16) in high half of u32 -> f32 value
__device__ __forceinline__ float key32_to_f(unsigned k32) {
    unsigned k16 = k32 >> 16;
    unsigned u16 = (k16 & 0x8000u) ? (k16 & 0x7FFFu) : (~k16 & 0xFFFFu);
    return __uint_as_float(u16 << 16);
}
// bf16 RNE round of f32, returns u16 pattern
__device__ __forceinline__ unsigned bf16rne(float f) {
    unsigned u = __float_as_uint(f);
    return (u + 0x7FFFu + ((u >> 16) & 1u)) >> 16;
}
__device__ __forceinline__ float bf16lo_f(unsigned w) { return __uint_as_float((w & 0xFFFFu) << 16); }
__device__ __forceinline__ float bf16hi_f(unsigned w) { return __uint_as_float(w & 0xFFFF0000u); }

__global__ __launch_bounds__(256) void k_init(unsigned* __restrict__ bcnt,
                                              float* __restrict__ stripes) {
    int t = blockIdx.x * blockDim.x + threadIdx.x;
    if (t < NBKT) bcnt[t] = 0u;
    if (t < NSTRIPE * 128) stripes[t] = 0.f;
}

// Bin edges by dst>>6 into per-bucket contiguous runs.
__global__ __launch_bounds__(BIN_THREADS) void k_bin(const int* __restrict__ ei,
                                                     unsigned* __restrict__ bcnt,
                                                     unsigned* __restrict__ binned) {
    __shared__ unsigned hcnt[NBKT];
    __shared__ unsigned hbase[NBKT];
    int e0 = blockIdx.x * TILE;
    int ecount = min(TILE, N_EDGES - e0);
    if (ecount <= 0) return;

    for (int i = threadIdx.x; i < NBKT; i += BIN_THREADS) hcnt[i] = 0u;
    __syncthreads();
    for (int i = threadIdx.x; i < ecount; i += BIN_THREADS) {
        int dst = ei[N_EDGES + e0 + i];
        if ((unsigned)dst < N_NODES) atomicAdd(&hcnt[dst >> BKT_SHIFT], 1u);
    }
    __syncthreads();
    for (int i = threadIdx.x; i < NBKT; i += BIN_THREADS) {
        unsigned c = hcnt[i];
        hbase[i] = c ? atomicAdd(&bcnt[i], c) : 0u;
        hcnt[i] = 0u;
    }
    __syncthreads();
    for (int i = threadIdx.x; i < ecount; i += BIN_THREADS) {
        int src = ei[e0 + i];
        int dst = ei[N_EDGES + e0 + i];
        if ((unsigned)src >= N_NODES || (unsigned)dst >= N_NODES) continue;
        int bk = dst >> BKT_SHIFT;
        unsigned pos = hbase[bk] + atomicAdd(&hcnt[bk], 1u);
        if (pos < BKT_CAP)
            binned[(size_t)bk * BKT_CAP + pos] =
                ((unsigned)(dst & (BKT_NODES - 1)) << 17) | (unsigned)src;
    }
}

// MFMA GEMM: 128 nodes/block, bf16 16x16x32.
// A' = x@(W1-W2)+b -> Apb (bf16 pack); B = x@W2 -> Bkey (monotonic-key pack).
// k-mapping safety: A-frag holds x[m=lane&15][psi(hi,j)], B-frag holds
// W[psi(hi,j)][n=lane&15] with the SAME psi -> sum telescopes to the true dot
// product for any hardware k-bijection. C/D layout per m89: row=(l>>4)*4+r, col=l&15.
__global__ __launch_bounds__(256) void k_gemm(const float* __restrict__ x,
                                              const float* __restrict__ W,
                                              const float* __restrict__ b,
                                              unsigned* __restrict__ Apb,
                                              unsigned* __restrict__ Bkey) {
    __shared__ unsigned short WaT[64 * XSTR];   // [col][k] bf16 of W1-W2
    __shared__ unsigned short WbT[64 * XSTR];   // [col][k] bf16 of W2
    __shared__ unsigned short xB[128 * XSTR];   // [node][k] bf16 of x
    __shared__ float biasS[64];
    int t = threadIdx.x;
    int base = blockIdx.x * 128;

    // stage W transposed as bf16 (coalesced global reads; one-time LDS scatter)
    for (int p = t; p < 4096; p += 256) {
        int k = p >> 6, c = p & 63;
        float w1 = W[p];
        float w2 = W[4096 + p];
        WaT[c * XSTR + k] = (unsigned short)bf16rne(w1 - w2);
        WbT[c * XSTR + k] = (unsigned short)bf16rne(w2);
    }
    if (t < 64) biasS[t] = b[t];

    // stage x -> bf16 LDS: thread t: node = t>>1, 32 channels
    {
        int node = t >> 1;
        int c0 = (t & 1) * 32;
        int gnode = base + node;
        float v[32];
        if (gnode < N_NODES) {
            const float4* xp = (const float4*)(x + (size_t)gnode * 64 + c0);
#pragma unroll
            for (int i = 0; i < 8; ++i) {
                float4 f = xp[i];
                v[4 * i + 0] = f.x; v[4 * i + 1] = f.y;
                v[4 * i + 2] = f.z; v[4 * i + 3] = f.w;
            }
        } else {
#pragma unroll
            for (int i = 0; i < 32; ++i) v[i] = 0.f;
        }
        unsigned short* dst = &xB[node * XSTR + c0];
#pragma unroll
        for (int i = 0; i < 32; ++i) dst[i] = (unsigned short)bf16rne(v[i]);
    }
    __syncthreads();

    int w = t >> 6;   // wave 0..3
    int l = t & 63;
    int ln = l & 15;
    int hi = l >> 4;

    // B-frags in registers (shared across both 64-node phases)
    short8 wa[4][2], wb[4][2];
#pragma unroll
    for (int nt = 0; nt < 4; ++nt)
#pragma unroll
        for (int h = 0; h < 2; ++h) {
            wa[nt][h] = *(const short8*)&WaT[(nt * 16 + ln) * XSTR + h * 32 + hi * 8];
            wb[nt][h] = *(const short8*)&WbT[(nt * 16 + ln) * XSTR + h * 32 + hi * 8];
        }

#pragma unroll
    for (int ph = 0; ph < 2; ++ph) {
        int rowbase = ph * 64 + w * 16;
        short8 af[2];
#pragma unroll
        for (int h = 0; h < 2; ++h)
            af[h] = *(const short8*)&xB[(rowbase + ln) * XSTR + h * 32 + hi * 8];

        f32x4 acca[4], accb[4];
#pragma unroll
        for (int nt = 0; nt < 4; ++nt) {
            acca[nt] = (f32x4){0.f, 0.f, 0.f, 0.f};
            accb[nt] = (f32x4){0.f, 0.f, 0.f, 0.f};
#pragma unroll
            for (int h = 0; h < 2; ++h) {
                acca[nt] = __builtin_amdgcn_mfma_f32_16x16x32_bf16(af[h], wa[nt][h], acca[nt], 0, 0, 0);
                accb[nt] = __builtin_amdgcn_mfma_f32_16x16x32_bf16(af[h], wb[nt][h], accb[nt], 0, 0, 0);
            }
        }
        // epilogue: pack pairs via shfl_xor(1) (lanes l,l^1 hold cols c,c+1)
#pragma unroll
        for (int nt = 0; nt < 4; ++nt) {
            int col = nt * 16 + ln;
            float bias = biasS[col];
            int cp = nt * 8 + (ln >> 1);
#pragma unroll
            for (int r = 0; r < 4; ++r) {
                int node = base + rowbase + hi * 4 + r;
                unsigned a16 = bf16rne(acca[nt][r] + bias);
                unsigned aO = (unsigned)__shfl_xor((int)a16, 1, 64);
                unsigned r16 = bf16rne(accb[nt][r]);
                unsigned key16 = (r16 & 0x8000u) ? (~r16 & 0xFFFFu) : (r16 | 0x8000u);
                unsigned kO = (unsigned)__shfl_xor((int)key16, 1, 64);
                if (((l & 1) == 0) && node < N_NODES) {
                    Apb[(size_t)node * 32 + cp] = a16 | (aO << 16);
                    Bkey[(size_t)node * 32 + cp] = key16 | (kO << 16);
                }
            }
        }
    }
}

// One bucket (64 nodes) per block. Cooperative row gather: 4 lanes/edge,
// each lane 2 x uint4 -> exactly 2 coalesced 64B line requests per edge.
// LDS atomicMax in key space; finish = ELU + bf16 h + BN partials.
__global__ __launch_bounds__(256) void k_fused(const unsigned* __restrict__ bcnt,
                                               const unsigned* __restrict__ binned,
                                               const unsigned* __restrict__ Bkey,
                                               const unsigned* __restrict__ Apb,
                                               unsigned* __restrict__ hpk,
                                               float* __restrict__ stripes) {
    extern __shared__ unsigned mx[];  // BKT_NODES*MAXW u32 = 16640 B
    int q = blockIdx.x;
    int t = threadIdx.x;
    int n0 = q * BKT_NODES;
    int nspan = min(BKT_NODES, N_NODES - n0);

    for (int i = t; i < BKT_NODES * MAXW; i += 256) mx[i] = 0u;
    __syncthreads();

    unsigned cnt = min(bcnt[q], (unsigned)BKT_CAP);
    const unsigned* lst = binned + (size_t)q * BKT_CAP;
    int ls = t & 3;
    for (unsigned i = (unsigned)(t >> 2); i < cnt; i += 64) {
        unsigned p = lst[i];
        unsigned src = p & 0x1FFFFu;
        unsigned dl = p >> 17;
        const uint4* bk = (const uint4*)(Bkey + (size_t)src * 32);
        uint4 w0 = bk[ls];
        uint4 w1 = bk[4 + ls];
        unsigned* row = mx + dl * MAXW;
        int s0 = ls * 8;
        atomicMax(&row[s0 + 0], w0.x << 16);
        atomicMax(&row[s0 + 1], w0.x & 0xFFFF0000u);
        atomicMax(&row[s0 + 2], w0.y << 16);
        atomicMax(&row[s0 + 3], w0.y & 0xFFFF0000u);
        atomicMax(&row[s0 + 4], w0.z << 16);
        atomicMax(&row[s0 + 5], w0.z & 0xFFFF0000u);
        atomicMax(&row[s0 + 6], w0.w << 16);
        atomicMax(&row[s0 + 7], w0.w & 0xFFFF0000u);
        int s1 = 32 + ls * 8;
        atomicMax(&row[s1 + 0], w1.x << 16);
        atomicMax(&row[s1 + 1], w1.x & 0xFFFF0000u);
        atomicMax(&row[s1 + 2], w1.y << 16);
        atomicMax(&row[s1 + 3], w1.y & 0xFFFF0000u);
        atomicMax(&row[s1 + 4], w1.z << 16);
        atomicMax(&row[s1 + 5], w1.z & 0xFFFF0000u);
        atomicMax(&row[s1 + 6], w1.w << 16);
        atomicMax(&row[s1 + 7], w1.w & 0xFFFF0000u);
    }
    __syncthreads();

    int lane4 = t & 15;
    int g = t >> 4;
    float4 s = make_float4(0.f, 0.f, 0.f, 0.f);
    float4 sq = make_float4(0.f, 0.f, 0.f, 0.f);
    for (int nl = g; nl < nspan; nl += 16) {
        int n = n0 + nl;
        const unsigned* row = mx + nl * MAXW + lane4 * 4;
        unsigned k0 = row[0], k1 = row[1], k2 = row[2], k3 = row[3];
        uint2 ap = *reinterpret_cast<const uint2*>(Apb + (size_t)n * 32 + lane4 * 2);
        float h0 = (k0 == 0u) ? 0.f : eluf(bf16lo_f(ap.x) + key32_to_f(k0));
        float h1 = (k1 == 0u) ? 0.f : eluf(bf16hi_f(ap.x) + key32_to_f(k1));
        float h2 = (k2 == 0u) ? 0.f : eluf(bf16lo_f(ap.y) + key32_to_f(k2));
        float h3 = (k3 == 0u) ? 0.f : eluf(bf16hi_f(ap.y) + key32_to_f(k3));
        unsigned q0 = bf16rne(h0), q1 = bf16rne(h1), q2 = bf16rne(h2), q3 = bf16rne(h3);
        uint2 hp;
        hp.x = q0 | (q1 << 16);
        hp.y = q2 | (q3 << 16);
        *reinterpret_cast<uint2*>(hpk + (size_t)n * 32 + lane4 * 2) = hp;
        float f0 = __uint_as_float(q0 << 16), f1 = __uint_as_float(q1 << 16);
        float f2 = __uint_as_float(q2 << 16), f3 = __uint_as_float(q3 << 16);
        s.x += f0; s.y += f1; s.z += f2; s.w += f3;
        sq.x += f0 * f0; sq.y += f1 * f1; sq.z += f2 * f2; sq.w += f3 * f3;
    }
    __syncthreads();

    float4* lsum = (float4*)mx;
    float4* lqum = lsum + 256;
    lsum[t] = s;
    lqum[t] = sq;
    __syncthreads();
#pragma unroll
    for (int off = 8; off >= 1; off >>= 1) {
        if (g < off) {
            int o = t + off * 16;
            lsum[t].x += lsum[o].x; lsum[t].y += lsum[o].y; lsum[t].z += lsum[o].z; lsum[t].w += lsum[o].w;
            lqum[t].x += lqum[o].x; lqum[t].y += lqum[o].y; lqum[t].z += lqum[o].z; lqum[t].w += lqum[o].w;
        }
        __syncthreads();
    }
    if (g == 0) {
        float* sb = stripes + (q & (NSTRIPE - 1)) * 128;
        int c4 = lane4 * 4;
        atomicAdd(&sb[c4 + 0], lsum[t].x);
        atomicAdd(&sb[c4 + 1], lsum[t].y);
        atomicAdd(&sb[c4 + 2], lsum[t].z);
        atomicAdd(&sb[c4 + 3], lsum[t].w);
        atomicAdd(&sb[64 + c4 + 0], lqum[t].x);
        atomicAdd(&sb[64 + c4 + 1], lqum[t].y);
        atomicAdd(&sb[64 + c4 + 2], lqum[t].z);
        atomicAdd(&sb[64 + c4 + 3], lqum[t].w);
    }
}

// fold 32 stripes -> 128 finals
__global__ __launch_bounds__(128) void k_reduce(const float* __restrict__ stripes,
                                                float* __restrict__ finals) {
    int t = threadIdx.x;
    float acc = 0.f;
#pragma unroll
    for (int s = 0; s < NSTRIPE; ++s) acc += stripes[s * 128 + t];
    finals[t] = acc;
}

// out = gamma*(h-mean)*rsqrt(var+eps)+beta; reads bf16-packed h, writes f32
__global__ __launch_bounds__(256) void k_bn(const uint2* __restrict__ hpk2,
                                            const float* __restrict__ finals,
                                            const float* __restrict__ gamma,
                                            const float* __restrict__ beta,
                                            float4* __restrict__ out4) {
    size_t i = (size_t)blockIdx.x * blockDim.x + threadIdx.x;
    size_t stride = (size_t)gridDim.x * blockDim.x;
    const float invN = 1.f / (float)N_NODES;
    size_t total4 = (size_t)N_NODES * C / 4;
    for (size_t p = i; p < total4; p += stride) {
        int c4 = (int)(p & 15) * 4;
        uint2 hp = hpk2[p];
        float hx = bf16lo_f(hp.x), hy = bf16hi_f(hp.x);
        float hz = bf16lo_f(hp.y), hw = bf16hi_f(hp.y);
        float4 o;
        float m, v, inv;
        m = finals[c4 + 0] * invN; v = finals[64 + c4 + 0] * invN - m * m; inv = rsqrtf(v + BN_EPS);
        o.x = gamma[c4 + 0] * (hx - m) * inv + beta[c4 + 0];
        m = finals[c4 + 1] * invN; v = finals[64 + c4 + 1] * invN - m * m; inv = rsqrtf(v + BN_EPS);
        o.y = gamma[c4 + 1] * (hy - m) * inv + beta[c4 + 1];
        m = finals[c4 + 2] * invN; v = finals[64 + c4 + 2] * invN - m * m; inv = rsqrtf(v + BN_EPS);
        o.z = gamma[c4 + 2] * (hz - m) * inv + beta[c4 + 2];
        m = finals[c4 + 3] * invN; v = finals[64 + c4 + 3] * invN - m * m; inv = rsqrtf(v + BN_EPS);
        o.w = gamma[c4 + 3] * (hw - m) * inv + beta[c4 + 3];
        out4[p] = o;
    }
}

extern "C" void kernel_launch(void* const* d_in, const int* in_sizes, int n_in,
                              void* d_out, int out_size, void* d_ws, size_t ws_size,
                              hipStream_t stream) {
    const float* x = (const float*)d_in[0];
    const int* ei = (const int*)d_in[1];  // int32 per harness contract
    const float* W = (const float*)d_in[2];
    const float* b = (const float*)d_in[3];
    const float* gamma = (const float*)d_in[4];
    const float* beta = (const float*)d_in[5];
    float* out = (float*)d_out;

    char* ws = (char*)d_ws;
    unsigned* Bkey = (unsigned*)ws;                                        // 12.8 MB
    unsigned* binned = (unsigned*)(ws + (size_t)N_NODES * 32 * 4);         // 12.8 MB
    unsigned* Apb = (unsigned*)((char*)binned + (size_t)NBKT * BKT_CAP * 4);   // 12.8 MB
    unsigned* hpk = Apb + (size_t)N_NODES * 32;                            // 12.8 MB
    unsigned* bcnt = hpk + (size_t)N_NODES * 32;
    float* stripes = (float*)((char*)bcnt + ((NBKT * 4 + 255) & ~255));
    float* finals = stripes + NSTRIPE * 128;

    k_init<<<(NSTRIPE * 128 + NBKT + 255) / 256, 256, 0, stream>>>(bcnt, stripes);
    k_bin<<<(N_EDGES + TILE - 1) / TILE, BIN_THREADS, 0, stream>>>(ei, bcnt, binned);
    k_gemm<<<(N_NODES + 127) / 128, 256, 0, stream>>>(x, W, b, Apb, Bkey);
    k_fused<<<NBKT, 256, BKT_NODES * MAXW * 4, stream>>>(bcnt, binned, Bkey, Apb, hpk, stripes);
    k_reduce<<<1, 128, 0, stream>>>(stripes, finals);
    k_bn<<<2048, 256, 0, stream>>>((const uint2*)hpk, finals, gamma, beta, (float4*)out);
}